// Round 2
// baseline (179.682 us; speedup 1.0000x reference)
//
#include <hip/hip_runtime.h>
#include <math.h>

#define N1 512
#define N2 512
#define DIN 1280
#define DD 100
#define HH 20
#define KS 7
#define NPIX (N1*N2)
#define PB 57

// workspace layout in floats
static constexpr size_t WS_PP    = 0;                      // 2*1024*100 = 204800
static constexpr size_t WS_W2T   = 204800;                 // 100*40 -> pad 4096
static constexpr size_t WS_M     = 204800 + 4096;          // 20*512*512 = 5242880
static constexpr size_t WS_CONV  = WS_M + 5242880;         // 262144
static constexpr size_t WS_STATS = WS_CONV + 262144;       // 64
static constexpr size_t WS_B     = WS_STATS + 64;          // 57*57 = 3249

// ---- repack W2 [20][200] -> w2t [100][40]
__global__ void kW(const float* __restrict__ W2, float* __restrict__ w2t) {
  int idx = blockIdx.x * 256 + threadIdx.x;
  if (idx >= DD * 2 * HH) return;
  int d = idx / (2 * HH), c = idx % (2 * HH);
  w2t[idx] = (c < HH) ? W2[c * 200 + d] : W2[(c - HH) * 200 + 100 + d];
}

// ---- projection partials: pp[kh][row][h] = sum_{k in half kh} x[row][k]*W1[h][k]
// rows 0..511 from x1, 512..1023 from x2. b1 added later at kB staging.
__global__ __launch_bounds__(256) void kA(const float* __restrict__ x1,
                                          const float* __restrict__ x2,
                                          const float* __restrict__ W1,
                                          float* __restrict__ pp) {
  const int bi = blockIdx.x >> 1, kh = blockIdx.x & 1;
  const int tid = threadIdx.x;
  const int h = tid & 127;
  const int rq = __builtin_amdgcn_readfirstlane(tid >> 7);  // wave-uniform row group
  const int r0 = bi * 4 + rq * 2;
  const float* xb = (r0 < N1) ? (x1 + (size_t)r0 * DIN) : (x2 + (size_t)(r0 - N1) * DIN);
  if (h >= DD) return;
  const float4* wr  = (const float4*)(W1 + (size_t)h * DIN) + kh * 160;
  const float4* xr0 = (const float4*)xb + kh * 160;
  const float4* xr1 = (const float4*)(xb + DIN) + kh * 160;
  float4 s0 = {0.f, 0.f, 0.f, 0.f}, s1 = {0.f, 0.f, 0.f, 0.f};
  for (int k = 0; k < 160; ++k) {
    float4 w = wr[k], v0 = xr0[k], v1 = xr1[k];
    s0.x = fmaf(w.x, v0.x, s0.x); s0.y = fmaf(w.y, v0.y, s0.y);
    s0.z = fmaf(w.z, v0.z, s0.z); s0.w = fmaf(w.w, v0.w, s0.w);
    s1.x = fmaf(w.x, v1.x, s1.x); s1.y = fmaf(w.y, v1.y, s1.y);
    s1.z = fmaf(w.z, v1.z, s1.z); s1.w = fmaf(w.w, v1.w, s1.w);
  }
  float a0 = (s0.x + s0.y) + (s0.z + s0.w);
  float a1 = (s1.x + s1.y) + (s1.z + s1.w);
  pp[(size_t)kh * 102400 + (size_t)r0 * DD + h] = a0;
  pp[(size_t)kh * 102400 + (size_t)(r0 + 1) * DD + h] = a1;
}

// ---- pairwise features + FC2 (raw m, pre-BN) + BN1 stats accumulation
__global__ __launch_bounds__(256) void kB(const float* __restrict__ pp,
                                          const float* __restrict__ b1,
                                          const float* __restrict__ w2t,
                                          float* __restrict__ m,
                                          float* __restrict__ stats) {
  __shared__ __align__(16) float sA[16][108];
  __shared__ __align__(16) float sC[16][108];
  __shared__ float wred[4][2 * HH];
  const int tid = threadIdx.x;
  const int bi = blockIdx.x >> 5, bj = blockIdx.x & 31;
  for (int idx = tid; idx < 16 * DD; idx += 256) {
    int r = idx / DD, d = idx % DD;
    float bv = b1[d];
    size_t ra = (size_t)(bi * 16 + r) * DD + d;
    size_t rc = (size_t)(N1 + bj * 16 + r) * DD + d;
    sA[r][d] = pp[ra] + pp[102400 + ra] + bv;
    sC[r][d] = pp[rc] + pp[102400 + rc] + bv;
  }
  __syncthreads();
  const int ti = tid >> 4, tj = tid & 15;
  float acc[HH];
#pragma unroll
  for (int h = 0; h < HH; ++h) acc[h] = 0.0f;
  const float4* sA4 = (const float4*)(&sA[ti][0]);
  const float4* sC4 = (const float4*)(&sC[tj][0]);
  for (int kq = 0; kq < DD / 4; ++kq) {
    float4 av = sA4[kq], cv = sC4[kq];
    float dif[4] = {fabsf(av.x - cv.x), fabsf(av.y - cv.y),
                    fabsf(av.z - cv.z), fabsf(av.w - cv.w)};
    float prd[4] = {av.x * cv.x, av.y * cv.y, av.z * cv.z, av.w * cv.w};
#pragma unroll
    for (int e = 0; e < 4; ++e) {
      const float* wrow = w2t + (size_t)(kq * 4 + e) * (2 * HH);  // uniform -> s_load
#pragma unroll
      for (int h = 0; h < HH; ++h) {
        acc[h] = fmaf(wrow[h], dif[e], acc[h]);
        acc[h] = fmaf(wrow[HH + h], prd[e], acc[h]);
      }
    }
  }
  const int gi = bi * 16 + ti, gj = bj * 16 + tj;
  const int lane = tid & 63, wv = tid >> 6;
#pragma unroll
  for (int h = 0; h < HH; ++h) {
    m[(size_t)h * NPIX + (size_t)gi * N2 + gj] = acc[h];
    float s = acc[h], q = acc[h] * acc[h];
#pragma unroll
    for (int off = 32; off; off >>= 1) {
      s += __shfl_xor(s, off);
      q += __shfl_xor(q, off);
    }
    if (lane == 0) { wred[wv][h] = s; wred[wv][HH + h] = q; }
  }
  __syncthreads();
  if (tid < 2 * HH) {
    float s = wred[0][tid] + wred[1][tid] + wred[2][tid] + wred[3][tid];
    atomicAdd(&stats[tid], s);
  }
}

// ---- conv 7x7 (20ch -> 1), BN1+relu at staging, register-tiled 2x2/thread
__global__ __launch_bounds__(256) void kD(const float* __restrict__ m,
                                          const float* __restrict__ bn1g,
                                          const float* __restrict__ bn1b,
                                          const float* __restrict__ cw,
                                          float* __restrict__ convOut,
                                          float* __restrict__ stats) {
  __shared__ float sIn[4][38][42];   // chunk of 4 channels, row stride 42
  __shared__ float sScale[HH], sShift[HH];
  __shared__ float wred[4][2];
  const int tid = threadIdx.x;
  if (tid < HH) {
    float s = stats[tid], q = stats[HH + tid];
    float mu = s * (1.0f / NPIX);
    float var = q * (1.0f / NPIX) - mu * mu;
    float rs = 1.0f / sqrtf(var + 1e-5f);
    float g = bn1g[tid] * rs;
    sScale[tid] = g;
    sShift[tid] = bn1b[tid] - mu * g;
  }
  __syncthreads();
  const int by = (blockIdx.x >> 4) * 32, bx = (blockIdx.x & 15) * 32;
  const int ty = tid >> 4, tx = tid & 15;
  float acc00 = 0.f, acc01 = 0.f, acc10 = 0.f, acc11 = 0.f;
#pragma unroll 1
  for (int cc = 0; cc < 5; ++cc) {
    if (cc) __syncthreads();
    for (int idx = tid; idx < 4 * 38 * 40; idx += 256) {
      int ch4 = idx / (38 * 40), rem = idx % (38 * 40);
      int r = rem / 40, c = rem % 40;
      int ch = cc * 4 + ch4;
      int gy = by + r - 3, gx = bx + c - 4;
      float v = 0.0f;
      if (gy >= 0 && gy < N1 && gx >= 0 && gx < N2)
        v = fmaxf(m[(size_t)ch * NPIX + (size_t)gy * N2 + gx] * sScale[ch] + sShift[ch], 0.0f);
      sIn[ch4][r][c] = v;
    }
    __syncthreads();
#pragma unroll 1
    for (int ch4 = 0; ch4 < 4; ++ch4) {
      float2 wv[8][5];   // 8x10 window, read once per channel
#pragma unroll
      for (int rr = 0; rr < 8; ++rr)
#pragma unroll
        for (int qq = 0; qq < 5; ++qq)
          wv[rr][qq] = *(const float2*)&sIn[ch4][2 * ty + rr][2 * tx + 2 * qq];
      const float* wch = cw + (cc * 4 + ch4) * 49;  // uniform -> s_load
#pragma unroll
      for (int ky = 0; ky < 7; ++ky)
#pragma unroll
        for (int kx = 0; kx < 7; ++kx) {
          float wt = wch[ky * 7 + kx];
          float e0 = ((kx + 1) & 1) ? wv[ky][(kx + 1) >> 1].y : wv[ky][(kx + 1) >> 1].x;
          float e1 = ((kx + 2) & 1) ? wv[ky][(kx + 2) >> 1].y : wv[ky][(kx + 2) >> 1].x;
          float f0 = ((kx + 1) & 1) ? wv[ky + 1][(kx + 1) >> 1].y : wv[ky + 1][(kx + 1) >> 1].x;
          float f1 = ((kx + 2) & 1) ? wv[ky + 1][(kx + 2) >> 1].y : wv[ky + 1][(kx + 2) >> 1].x;
          acc00 = fmaf(e0, wt, acc00);
          acc01 = fmaf(e1, wt, acc01);
          acc10 = fmaf(f0, wt, acc10);
          acc11 = fmaf(f1, wt, acc11);
        }
    }
  }
  const int oy = by + 2 * ty, ox = bx + 2 * tx;
  float2 r0 = {acc00, acc01}, r1 = {acc10, acc11};
  *(float2*)&convOut[(size_t)oy * N2 + ox] = r0;
  *(float2*)&convOut[(size_t)(oy + 1) * N2 + ox] = r1;
  float s = acc00 + acc01 + acc10 + acc11;
  float q = acc00 * acc00 + acc01 * acc01 + acc10 * acc10 + acc11 * acc11;
  const int lane = tid & 63, wvi = tid >> 6;
#pragma unroll
  for (int off = 32; off; off >>= 1) {
    s += __shfl_xor(s, off);
    q += __shfl_xor(q, off);
  }
  if (lane == 0) { wred[wvi][0] = s; wred[wvi][1] = q; }
  __syncthreads();
  if (tid < 2) {
    float v = wred[0][tid] + wred[1][tid] + wred[2][tid] + wred[3][tid];
    atomicAdd(&stats[2 * HH + tid], v);
  }
}

// ---- BN2 + sigmoid -> C (d_out[1:])
__global__ __launch_bounds__(256) void kE(const float* __restrict__ convOut,
                                          const float* __restrict__ stats,
                                          const float* __restrict__ bn2g,
                                          const float* __restrict__ bn2b,
                                          float* __restrict__ Cout) {
  const int i = blockIdx.x * 256 + threadIdx.x;
  float s = stats[2 * HH], q = stats[2 * HH + 1];
  float mu = s * (1.0f / NPIX);
  float var = q * (1.0f / NPIX) - mu * mu;
  float rs = 1.0f / sqrtf(var + 1e-5f);
  float g = bn2g[0] * rs;
  float b = bn2b[0] - mu * g;
  float z = convOut[i] * g + b;
  Cout[i] = 1.0f / (1.0f + expf(-z));
}

// ---- maxpool 9x9 stride 9 pad 4 -> B [57][57]
__global__ void kM(const float* __restrict__ C, float* __restrict__ B) {
  int p = blockIdx.x * 256 + threadIdx.x;
  if (p >= PB * PB) return;
  int wy = p / PB, wx = p % PB;
  int y0 = wy * 9 - 4, x0 = wx * 9 - 4;
  float mx = -1e30f;
  for (int dy = 0; dy < 9; ++dy) {
    int y = y0 + dy;
    if (y < 0 || y >= N1) continue;
    for (int dx = 0; dx < 9; ++dx) {
      int x = x0 + dx;
      if (x < 0 || x >= N2) continue;
      mx = fmaxf(mx, C[(size_t)y * N2 + x]);
    }
  }
  B[p] = mx;
}

// ---- per-column mean/std(ddof=1), Q=relu(B-mean-gamma*std), phat -> d_out[0]
__global__ __launch_bounds__(256) void kF(const float* __restrict__ B,
                                          const float* __restrict__ gamma,
                                          float* __restrict__ out0) {
  __shared__ float sB[PB * PB];
  __shared__ float cm[PB], cs[PB];
  __shared__ float r1[4], r2[4];
  const int tid = threadIdx.x;
  for (int i = tid; i < PB * PB; i += 256) sB[i] = B[i];
  __syncthreads();
  if (tid < PB) {
    float s = 0.0f;
    for (int h = 0; h < PB; ++h) s += sB[h * PB + tid];
    float mean = s / (float)PB;
    float v = 0.0f;
    for (int h = 0; h < PB; ++h) { float d = sB[h * PB + tid] - mean; v += d * d; }
    cm[tid] = mean;
    cs[tid] = sqrtf(v / (float)(PB - 1) + 1e-5f);
  }
  __syncthreads();
  const float g = gamma[0];
  float sq = 0.0f, cnt = 0.0f;
  for (int i = tid; i < PB * PB; i += 256) {
    int w = i % PB;
    float qv = sB[i] - cm[w] - g * cs[w];
    if (qv > 0.0f) { sq += qv; cnt += 1.0f; }
  }
#pragma unroll
  for (int off = 32; off; off >>= 1) {
    sq += __shfl_xor(sq, off);
    cnt += __shfl_xor(cnt, off);
  }
  if ((tid & 63) == 0) { r1[tid >> 6] = sq; r2[tid >> 6] = cnt; }
  __syncthreads();
  if (tid == 0) {
    float S = r1[0] + r1[1] + r1[2] + r1[3];
    float Cn = r2[0] + r2[1] + r2[2] + r2[3];
    float phat = S / (Cn + 1.0f);
    float sig = 1.0f / (1.0f + expf(-phat));
    out0[0] = fminf(fmaxf(sig, 0.0f), 1.0f);
  }
}

extern "C" void kernel_launch(void* const* d_in, const int* in_sizes, int n_in,
                              void* d_out, int out_size, void* d_ws, size_t ws_size,
                              hipStream_t stream) {
  const float* x1    = (const float*)d_in[0];
  const float* x2    = (const float*)d_in[1];
  const float* W1    = (const float*)d_in[2];
  const float* b1    = (const float*)d_in[3];
  const float* W2    = (const float*)d_in[4];
  // d_in[5] = b2   : cancels exactly through BN1 (training-mode mean subtraction)
  const float* bn1g  = (const float*)d_in[6];
  const float* bn1b  = (const float*)d_in[7];
  const float* convw = (const float*)d_in[8];
  // d_in[9] = conv_b : cancels exactly through BN2
  const float* bn2g  = (const float*)d_in[10];
  const float* bn2b  = (const float*)d_in[11];
  const float* gamma = (const float*)d_in[12];

  float* ws    = (float*)d_ws;
  float* pp    = ws + WS_PP;
  float* w2t   = ws + WS_W2T;
  float* m     = ws + WS_M;
  float* conv  = ws + WS_CONV;
  float* stats = ws + WS_STATS;
  float* Bp    = ws + WS_B;
  float* out   = (float*)d_out;

  hipMemsetAsync(stats, 0, 64 * sizeof(float), stream);
  kW<<<(DD * 2 * HH + 255) / 256, 256, 0, stream>>>(W2, w2t);
  kA<<<512, 256, 0, stream>>>(x1, x2, W1, pp);
  kB<<<1024, 256, 0, stream>>>(pp, b1, w2t, m, stats);
  kD<<<256, 256, 0, stream>>>(m, bn1g, bn1b, convw, conv, stats);
  kE<<<1024, 256, 0, stream>>>(conv, stats, bn2g, bn2b, out + 1);
  kM<<<(PB * PB + 255) / 256, 256, 0, stream>>>(out + 1, Bp);
  kF<<<1, 256, 0, stream>>>(Bp, gamma, out);
}

// Round 3
// 142.061 us; speedup vs baseline: 1.2648x; 1.2648x over previous
//
#include <hip/hip_runtime.h>
#include <math.h>

#define N1 512
#define N2 512
#define DIN 1280
#define DD 100
#define HH 20
#define NPIX (N1*N2)
#define PB 57

// workspace layout in floats
static constexpr size_t WS_PP    = 0;                      // 2*1024*100 = 204800
static constexpr size_t WS_W2T   = 204800;                 // 100*40 -> pad 4096
static constexpr size_t WS_M     = 204800 + 4096;          // 20*512*512 = 5242880
static constexpr size_t WS_PART  = WS_M + 5242880;         // 5*262144 = 1310720
static constexpr size_t WS_STATS = WS_PART + 1310720;      // 64
static constexpr size_t WS_B     = WS_STATS + 64;          // 57*57 = 3249

// ---- repack W2 [20][200] -> w2t [100][40]; also zero stats
__global__ void kW(const float* __restrict__ W2, float* __restrict__ w2t,
                   float* __restrict__ stats) {
  int idx = blockIdx.x * 256 + threadIdx.x;
  if (blockIdx.x == 0 && threadIdx.x < 64) stats[threadIdx.x] = 0.0f;
  if (idx >= DD * 2 * HH) return;
  int d = idx / (2 * HH), c = idx % (2 * HH);
  w2t[idx] = (c < HH) ? W2[c * 200 + d] : W2[(c - HH) * 200 + 100 + d];
}

// ---- projection partials: pp[kh][row][h]
__global__ __launch_bounds__(256) void kA(const float* __restrict__ x1,
                                          const float* __restrict__ x2,
                                          const float* __restrict__ W1,
                                          float* __restrict__ pp) {
  const int bi = blockIdx.x >> 1, kh = blockIdx.x & 1;
  const int tid = threadIdx.x;
  const int h = tid & 127;
  const int rq = __builtin_amdgcn_readfirstlane(tid >> 7);  // wave-uniform row group
  const int r0 = bi * 4 + rq * 2;
  const float* xb = (r0 < N1) ? (x1 + (size_t)r0 * DIN) : (x2 + (size_t)(r0 - N1) * DIN);
  if (h >= DD) return;
  const float4* wr  = (const float4*)(W1 + (size_t)h * DIN) + kh * 160;
  const float4* xr0 = (const float4*)xb + kh * 160;
  const float4* xr1 = (const float4*)(xb + DIN) + kh * 160;
  float4 s0 = {0.f, 0.f, 0.f, 0.f}, s1 = {0.f, 0.f, 0.f, 0.f};
  for (int k = 0; k < 160; ++k) {
    float4 w = wr[k], v0 = xr0[k], v1 = xr1[k];
    s0.x = fmaf(w.x, v0.x, s0.x); s0.y = fmaf(w.y, v0.y, s0.y);
    s0.z = fmaf(w.z, v0.z, s0.z); s0.w = fmaf(w.w, v0.w, s0.w);
    s1.x = fmaf(w.x, v1.x, s1.x); s1.y = fmaf(w.y, v1.y, s1.y);
    s1.z = fmaf(w.z, v1.z, s1.z); s1.w = fmaf(w.w, v1.w, s1.w);
  }
  float a0 = (s0.x + s0.y) + (s0.z + s0.w);
  float a1 = (s1.x + s1.y) + (s1.z + s1.w);
  pp[(size_t)kh * 102400 + (size_t)r0 * DD + h] = a0;
  pp[(size_t)kh * 102400 + (size_t)(r0 + 1) * DD + h] = a1;
}

// ---- pairwise features + FC2 (packed-f32 path) + BN1 stats accumulation
__global__ __launch_bounds__(256) void kB(const float* __restrict__ pp,
                                          const float* __restrict__ b1,
                                          const float* __restrict__ w2t,
                                          float* __restrict__ m,
                                          float* __restrict__ stats) {
  __shared__ __align__(16) float sA[16][108];
  __shared__ __align__(16) float sC[16][108];
  __shared__ float wred[4][2 * HH];
  const int tid = threadIdx.x;
  const int bi = blockIdx.x >> 5, bj = blockIdx.x & 31;
  for (int idx = tid; idx < 16 * DD; idx += 256) {
    int r = idx / DD, d = idx % DD;
    float bv = b1[d];
    size_t ra = (size_t)(bi * 16 + r) * DD + d;
    size_t rc = (size_t)(N1 + bj * 16 + r) * DD + d;
    sA[r][d] = pp[ra] + pp[102400 + ra] + bv;
    sC[r][d] = pp[rc] + pp[102400 + rc] + bv;
  }
  __syncthreads();
  const int ti = tid >> 4, tj = tid & 15;
  float2 acc2[10];
#pragma unroll
  for (int j = 0; j < 10; ++j) acc2[j] = make_float2(0.f, 0.f);
  const float4* sA4 = (const float4*)(&sA[ti][0]);
  const float4* sC4 = (const float4*)(&sC[tj][0]);
  for (int kq = 0; kq < DD / 4; ++kq) {
    float4 av = sA4[kq], cv = sC4[kq];
    float d0 = fabsf(av.x - cv.x), d1 = fabsf(av.y - cv.y);
    float d2 = fabsf(av.z - cv.z), d3 = fabsf(av.w - cv.w);
    float p0 = av.x * cv.x, p1 = av.y * cv.y, p2 = av.z * cv.z, p3 = av.w * cv.w;
    float dd[4] = {d0, d1, d2, d3}, ppv[4] = {p0, p1, p2, p3};
#pragma unroll
    for (int e = 0; e < 4; ++e) {
      const float2* w2 = (const float2*)(w2t + (size_t)(kq * 4 + e) * (2 * HH));
      float2 de = make_float2(dd[e], dd[e]);
      float2 pe = make_float2(ppv[e], ppv[e]);
#pragma unroll
      for (int j = 0; j < 10; ++j) {
        acc2[j] += w2[j] * de;        // ffp-contract -> v_pk_fma_f32
        acc2[j] += w2[10 + j] * pe;
      }
    }
  }
  const int gi = bi * 16 + ti, gj = bj * 16 + tj;
  const int lane = tid & 63, wv = tid >> 6;
#pragma unroll
  for (int h = 0; h < HH; ++h) {
    float a = (h & 1) ? acc2[h >> 1].y : acc2[h >> 1].x;
    m[(size_t)h * NPIX + (size_t)gi * N2 + gj] = a;
    float s = a, q = a * a;
#pragma unroll
    for (int off = 32; off; off >>= 1) {
      s += __shfl_xor(s, off);
      q += __shfl_xor(q, off);
    }
    if (lane == 0) { wred[wv][h] = s; wred[wv][HH + h] = q; }
  }
  __syncthreads();
  if (tid < 2 * HH) {
    float s = wred[0][tid] + wred[1][tid] + wred[2][tid] + wred[3][tid];
    atomicAdd(&stats[tid], s);
  }
}

// ---- conv 7x7, 4 channels per block (5-way split), BN1+relu at staging
__global__ __launch_bounds__(256, 4) void kD(const float* __restrict__ m,
                                             const float* __restrict__ bn1g,
                                             const float* __restrict__ bn1b,
                                             const float* __restrict__ cw,
                                             const float* __restrict__ stats,
                                             float* __restrict__ part) {
  __shared__ float sIn[4][38][40];
  __shared__ float sSc[4], sSh[4];
  const int tid = threadIdx.x;
  const int cs = blockIdx.y;               // channel chunk 0..4
  if (tid < 4) {
    int ch = cs * 4 + tid;
    float s = stats[ch], q = stats[HH + ch];
    float mu = s * (1.0f / NPIX);
    float var = q * (1.0f / NPIX) - mu * mu;
    float g = bn1g[ch] / sqrtf(var + 1e-5f);
    sSc[tid] = g;
    sSh[tid] = bn1b[ch] - mu * g;
  }
  __syncthreads();
  const int by = (blockIdx.x >> 4) * 32, bx = (blockIdx.x & 15) * 32;
  for (int idx = tid; idx < 4 * 38 * 40; idx += 256) {
    int ch4 = idx / 1520, rem = idx % 1520;
    int r = rem / 40, c = rem % 40;
    int gy = by + r - 3, gx = bx + c - 4;
    float v = 0.0f;
    if (gy >= 0 && gy < N1 && gx >= 0 && gx < N2)
      v = fmaxf(m[(size_t)(cs * 4 + ch4) * NPIX + (size_t)gy * N2 + gx] * sSc[ch4] + sSh[ch4], 0.0f);
    sIn[ch4][r][c] = v;
  }
  __syncthreads();
  const int ty = tid >> 4, tx = tid & 15;
  float acc00 = 0.f, acc01 = 0.f, acc10 = 0.f, acc11 = 0.f;
#pragma unroll 1
  for (int ch4 = 0; ch4 < 4; ++ch4) {
    float2 wv[8][5];
#pragma unroll
    for (int rr = 0; rr < 8; ++rr)
#pragma unroll
      for (int qq = 0; qq < 5; ++qq)
        wv[rr][qq] = *(const float2*)&sIn[ch4][2 * ty + rr][2 * tx + 2 * qq];
    const float* wch = cw + (cs * 4 + ch4) * 49;   // uniform -> s_load
#pragma unroll
    for (int ky = 0; ky < 7; ++ky)
#pragma unroll
      for (int kx = 0; kx < 7; ++kx) {
        float wt = wch[ky * 7 + kx];
        float e0 = ((kx + 1) & 1) ? wv[ky][(kx + 1) >> 1].y : wv[ky][(kx + 1) >> 1].x;
        float e1 = ((kx + 2) & 1) ? wv[ky][(kx + 2) >> 1].y : wv[ky][(kx + 2) >> 1].x;
        float f0 = ((kx + 1) & 1) ? wv[ky + 1][(kx + 1) >> 1].y : wv[ky + 1][(kx + 1) >> 1].x;
        float f1 = ((kx + 2) & 1) ? wv[ky + 1][(kx + 2) >> 1].y : wv[ky + 1][(kx + 2) >> 1].x;
        acc00 = fmaf(e0, wt, acc00);
        acc01 = fmaf(e1, wt, acc01);
        acc10 = fmaf(f0, wt, acc10);
        acc11 = fmaf(f1, wt, acc11);
      }
  }
  const int oy = by + 2 * ty, ox = bx + 2 * tx;
  float2 r0 = {acc00, acc01}, r1 = {acc10, acc11};
  float* dst = part + (size_t)cs * NPIX;
  *(float2*)&dst[(size_t)oy * N2 + ox] = r0;
  *(float2*)&dst[(size_t)(oy + 1) * N2 + ox] = r1;
}

// ---- sum partials -> BN2 stats (atomic, f32, tiny)
__global__ __launch_bounds__(256) void kE1(const float* __restrict__ part,
                                           float* __restrict__ stats) {
  __shared__ float wred[4][2];
  const int i = blockIdx.x * 256 + threadIdx.x;
  float s = part[i] + part[NPIX + i] + part[2 * NPIX + i] + part[3 * NPIX + i] + part[4 * NPIX + i];
  float q = s * s;
  const int lane = threadIdx.x & 63, wv = threadIdx.x >> 6;
#pragma unroll
  for (int off = 32; off; off >>= 1) {
    s += __shfl_xor(s, off);
    q += __shfl_xor(q, off);
  }
  if (lane == 0) { wred[wv][0] = s; wred[wv][1] = q; }
  __syncthreads();
  if (threadIdx.x < 2) {
    float v = wred[0][threadIdx.x] + wred[1][threadIdx.x] + wred[2][threadIdx.x] + wred[3][threadIdx.x];
    atomicAdd(&stats[2 * HH + threadIdx.x], v);
  }
}

// ---- BN2 + sigmoid -> C (d_out[1:])
__global__ __launch_bounds__(256) void kE2(const float* __restrict__ part,
                                           const float* __restrict__ stats,
                                           const float* __restrict__ bn2g,
                                           const float* __restrict__ bn2b,
                                           float* __restrict__ Cout) {
  const int i = blockIdx.x * 256 + threadIdx.x;
  float s = stats[2 * HH], q = stats[2 * HH + 1];
  float mu = s * (1.0f / NPIX);
  float var = q * (1.0f / NPIX) - mu * mu;
  float g = bn2g[0] / sqrtf(var + 1e-5f);
  float b = bn2b[0] - mu * g;
  float z = (part[i] + part[NPIX + i] + part[2 * NPIX + i] + part[3 * NPIX + i] + part[4 * NPIX + i]) * g + b;
  Cout[i] = 1.0f / (1.0f + expf(-z));
}

// ---- maxpool 9x9 stride 9 pad 4: one wave per window
__global__ __launch_bounds__(256) void kM(const float* __restrict__ C, float* __restrict__ B) {
  const int w = blockIdx.x * 4 + (threadIdx.x >> 6);
  const int lane = threadIdx.x & 63;
  if (w >= PB * PB) return;
  const int wy = w / PB, wx = w % PB;
  const int y0 = wy * 9 - 4, x0 = wx * 9 - 4;
  float mx = -1e30f;
  for (int e = lane; e < 81; e += 64) {
    int y = y0 + e / 9, x = x0 + e % 9;
    if (y >= 0 && y < N1 && x >= 0 && x < N2)
      mx = fmaxf(mx, C[(size_t)y * N2 + x]);
  }
#pragma unroll
  for (int off = 32; off; off >>= 1) mx = fmaxf(mx, __shfl_xor(mx, off));
  if (lane == 0) B[w] = mx;
}

// ---- per-column mean/std(ddof=1), phat -> d_out[0]
__global__ __launch_bounds__(256) void kF(const float* __restrict__ B,
                                          const float* __restrict__ gamma,
                                          float* __restrict__ out0) {
  __shared__ float sB[PB * PB];
  __shared__ float cm[PB], cs[PB];
  __shared__ float r1[4], r2[4];
  const int tid = threadIdx.x;
  for (int i = tid; i < PB * PB; i += 256) sB[i] = B[i];
  __syncthreads();
  if (tid < PB) {
    float s = 0.0f;
    for (int h = 0; h < PB; ++h) s += sB[h * PB + tid];
    float mean = s / (float)PB;
    float v = 0.0f;
    for (int h = 0; h < PB; ++h) { float d = sB[h * PB + tid] - mean; v += d * d; }
    cm[tid] = mean;
    cs[tid] = sqrtf(v / (float)(PB - 1) + 1e-5f);
  }
  __syncthreads();
  const float g = gamma[0];
  float sq = 0.0f, cnt = 0.0f;
  for (int i = tid; i < PB * PB; i += 256) {
    int w = i % PB;
    float qv = sB[i] - cm[w] - g * cs[w];
    if (qv > 0.0f) { sq += qv; cnt += 1.0f; }
  }
#pragma unroll
  for (int off = 32; off; off >>= 1) {
    sq += __shfl_xor(sq, off);
    cnt += __shfl_xor(cnt, off);
  }
  if ((tid & 63) == 0) { r1[tid >> 6] = sq; r2[tid >> 6] = cnt; }
  __syncthreads();
  if (tid == 0) {
    float S = r1[0] + r1[1] + r1[2] + r1[3];
    float Cn = r2[0] + r2[1] + r2[2] + r2[3];
    float phat = S / (Cn + 1.0f);
    float sig = 1.0f / (1.0f + expf(-phat));
    out0[0] = fminf(fmaxf(sig, 0.0f), 1.0f);
  }
}

extern "C" void kernel_launch(void* const* d_in, const int* in_sizes, int n_in,
                              void* d_out, int out_size, void* d_ws, size_t ws_size,
                              hipStream_t stream) {
  const float* x1    = (const float*)d_in[0];
  const float* x2    = (const float*)d_in[1];
  const float* W1    = (const float*)d_in[2];
  const float* b1    = (const float*)d_in[3];
  const float* W2    = (const float*)d_in[4];
  // d_in[5] = b2   : cancels through BN1 (training-mode mean subtraction)
  const float* bn1g  = (const float*)d_in[6];
  const float* bn1b  = (const float*)d_in[7];
  const float* convw = (const float*)d_in[8];
  // d_in[9] = conv_b : cancels through BN2
  const float* bn2g  = (const float*)d_in[10];
  const float* bn2b  = (const float*)d_in[11];
  const float* gamma = (const float*)d_in[12];

  float* ws    = (float*)d_ws;
  float* pp    = ws + WS_PP;
  float* w2t   = ws + WS_W2T;
  float* m     = ws + WS_M;
  float* part  = ws + WS_PART;
  float* stats = ws + WS_STATS;
  float* Bp    = ws + WS_B;
  float* out   = (float*)d_out;

  kW<<<16, 256, 0, stream>>>(W2, w2t, stats);
  kA<<<512, 256, 0, stream>>>(x1, x2, W1, pp);
  kB<<<1024, 256, 0, stream>>>(pp, b1, w2t, m, stats);
  kD<<<dim3(256, 5), 256, 0, stream>>>(m, bn1g, bn1b, convw, stats, part);
  kE1<<<1024, 256, 0, stream>>>(part, stats);
  kE2<<<1024, 256, 0, stream>>>(part, stats, bn2g, bn2b, out + 1);
  kM<<<(PB * PB + 3) / 4, 256, 0, stream>>>(out + 1, Bp);
  kF<<<1, 256, 0, stream>>>(Bp, gamma, out);
}

// Round 4
// 138.923 us; speedup vs baseline: 1.2934x; 1.0226x over previous
//
#include <hip/hip_runtime.h>
#include <math.h>

#define N1 512
#define N2 512
#define DIN 1280
#define DD 100
#define HH 20
#define NPIX (N1*N2)
#define PB 57

// workspace layout in floats
static constexpr size_t WS_PP    = 0;                      // 4*1024*100 = 409600
static constexpr size_t WS_W2T   = 409600;                 // 100*40 -> pad 4096
static constexpr size_t WS_M     = 409600 + 4096;          // 20*512*512 = 5242880
static constexpr size_t WS_PART  = WS_M + 5242880;         // 5*262144 = 1310720
static constexpr size_t WS_STATS = WS_PART + 1310720;      // 64
static constexpr size_t WS_B     = WS_STATS + 64;          // 57*57 = 3249

// ---- repack W2 [20][200] -> w2t [100][40]; also zero stats
__global__ void kW(const float* __restrict__ W2, float* __restrict__ w2t,
                   float* __restrict__ stats) {
  int idx = blockIdx.x * 256 + threadIdx.x;
  if (blockIdx.x == 0 && threadIdx.x < 64) stats[threadIdx.x] = 0.0f;
  if (idx >= DD * 2 * HH) return;
  int d = idx / (2 * HH), c = idx % (2 * HH);
  w2t[idx] = (c < HH) ? W2[c * 200 + d] : W2[(c - HH) * 200 + 100 + d];
}

// ---- projection partials, 4-way K split: pp[kh][row][h], kh in 0..3 (K=320 each)
__global__ __launch_bounds__(256) void kA(const float* __restrict__ x1,
                                          const float* __restrict__ x2,
                                          const float* __restrict__ W1,
                                          float* __restrict__ pp) {
  const int bi = blockIdx.x >> 2, kh = blockIdx.x & 3;
  const int tid = threadIdx.x;
  const int h = tid & 127;
  const int rq = __builtin_amdgcn_readfirstlane(tid >> 7);  // wave-uniform row group
  const int r0 = bi * 4 + rq * 2;
  const float* xb = (r0 < N1) ? (x1 + (size_t)r0 * DIN) : (x2 + (size_t)(r0 - N1) * DIN);
  if (h >= DD) return;
  const float4* wr  = (const float4*)(W1 + (size_t)h * DIN) + kh * 80;
  const float4* xr0 = (const float4*)xb + kh * 80;
  const float4* xr1 = (const float4*)(xb + DIN) + kh * 80;
  float4 s0 = {0.f, 0.f, 0.f, 0.f}, s1 = {0.f, 0.f, 0.f, 0.f};
  for (int k = 0; k < 80; ++k) {
    float4 w = wr[k], v0 = xr0[k], v1 = xr1[k];
    s0.x = fmaf(w.x, v0.x, s0.x); s0.y = fmaf(w.y, v0.y, s0.y);
    s0.z = fmaf(w.z, v0.z, s0.z); s0.w = fmaf(w.w, v0.w, s0.w);
    s1.x = fmaf(w.x, v1.x, s1.x); s1.y = fmaf(w.y, v1.y, s1.y);
    s1.z = fmaf(w.z, v1.z, s1.z); s1.w = fmaf(w.w, v1.w, s1.w);
  }
  float a0 = (s0.x + s0.y) + (s0.z + s0.w);
  float a1 = (s1.x + s1.y) + (s1.z + s1.w);
  pp[(size_t)kh * 102400 + (size_t)r0 * DD + h] = a0;
  pp[(size_t)kh * 102400 + (size_t)(r0 + 1) * DD + h] = a1;
}

// ---- pairwise features + FC2, 2 pixels/thread (16x32 tile) + BN1 stats
__global__ __launch_bounds__(256, 2) void kB(const float* __restrict__ pp,
                                             const float* __restrict__ b1,
                                             const float* __restrict__ w2t,
                                             float* __restrict__ m,
                                             float* __restrict__ stats) {
  __shared__ __align__(16) float sA[16][108];
  __shared__ __align__(16) float sC[32][108];
  __shared__ float wred[4][2 * HH];
  const int tid = threadIdx.x;
  const int bi = blockIdx.x >> 4, bj = blockIdx.x & 15;   // 32 x 16 tiles
  for (int idx = tid; idx < 48 * DD; idx += 256) {
    int r = idx / DD, d = idx % DD;
    float bv = b1[d];
    if (r < 16) {
      size_t ra = (size_t)(bi * 16 + r) * DD + d;
      sA[r][d] = pp[ra] + pp[102400 + ra] + pp[204800 + ra] + pp[307200 + ra] + bv;
    } else {
      size_t rc = (size_t)(N1 + bj * 32 + (r - 16)) * DD + d;
      sC[r - 16][d] = pp[rc] + pp[102400 + rc] + pp[204800 + rc] + pp[307200 + rc] + bv;
    }
  }
  __syncthreads();
  const int ti = tid >> 4, tj = tid & 15;   // pixels (ti,tj) and (ti,tj+16)
  float acc0[HH], acc1[HH];
#pragma unroll
  for (int h = 0; h < HH; ++h) { acc0[h] = 0.0f; acc1[h] = 0.0f; }
  const float4* sA4 = (const float4*)(&sA[ti][0]);
  const float4* sC4a = (const float4*)(&sC[tj][0]);
  const float4* sC4b = (const float4*)(&sC[tj + 16][0]);
  for (int kq = 0; kq < DD / 4; ++kq) {
    float4 av = sA4[kq], ca = sC4a[kq], cb = sC4b[kq];
    float da[4] = {fabsf(av.x - ca.x), fabsf(av.y - ca.y),
                   fabsf(av.z - ca.z), fabsf(av.w - ca.w)};
    float pa[4] = {av.x * ca.x, av.y * ca.y, av.z * ca.z, av.w * ca.w};
    float db[4] = {fabsf(av.x - cb.x), fabsf(av.y - cb.y),
                   fabsf(av.z - cb.z), fabsf(av.w - cb.w)};
    float pb[4] = {av.x * cb.x, av.y * cb.y, av.z * cb.z, av.w * cb.w};
#pragma unroll
    for (int e = 0; e < 4; ++e) {
      const float* w = w2t + (size_t)(kq * 4 + e) * (2 * HH);  // uniform -> s_load
#pragma unroll
      for (int h = 0; h < HH; ++h) {
        acc0[h] = fmaf(w[h], da[e], acc0[h]);
        acc0[h] = fmaf(w[HH + h], pa[e], acc0[h]);
        acc1[h] = fmaf(w[h], db[e], acc1[h]);
        acc1[h] = fmaf(w[HH + h], pb[e], acc1[h]);
      }
    }
  }
  const int gi = bi * 16 + ti, gj = bj * 32 + tj;
  const int lane = tid & 63, wv = tid >> 6;
#pragma unroll
  for (int h = 0; h < HH; ++h) {
    m[(size_t)h * NPIX + (size_t)gi * N2 + gj] = acc0[h];
    m[(size_t)h * NPIX + (size_t)gi * N2 + gj + 16] = acc1[h];
    float s = acc0[h] + acc1[h];
    float q = acc0[h] * acc0[h] + acc1[h] * acc1[h];
#pragma unroll
    for (int off = 32; off; off >>= 1) {
      s += __shfl_xor(s, off);
      q += __shfl_xor(q, off);
    }
    if (lane == 0) { wred[wv][h] = s; wred[wv][HH + h] = q; }
  }
  __syncthreads();
  if (tid < 2 * HH) {
    float s = wred[0][tid] + wred[1][tid] + wred[2][tid] + wred[3][tid];
    atomicAdd(&stats[tid], s);
  }
}

// ---- conv 7x7, 4 channels per block (5-way split), BN1+relu at staging
__global__ __launch_bounds__(256, 4) void kD(const float* __restrict__ m,
                                             const float* __restrict__ bn1g,
                                             const float* __restrict__ bn1b,
                                             const float* __restrict__ cw,
                                             const float* __restrict__ stats,
                                             float* __restrict__ part) {
  __shared__ float sIn[4][38][40];
  __shared__ float sSc[4], sSh[4];
  const int tid = threadIdx.x;
  const int cs = blockIdx.y;               // channel chunk 0..4
  if (tid < 4) {
    int ch = cs * 4 + tid;
    float s = stats[ch], q = stats[HH + ch];
    float mu = s * (1.0f / NPIX);
    float var = q * (1.0f / NPIX) - mu * mu;
    float g = bn1g[ch] / sqrtf(var + 1e-5f);
    sSc[tid] = g;
    sSh[tid] = bn1b[ch] - mu * g;
  }
  __syncthreads();
  const int by = (blockIdx.x >> 4) * 32, bx = (blockIdx.x & 15) * 32;
  for (int idx = tid; idx < 4 * 38 * 40; idx += 256) {
    int ch4 = idx / 1520, rem = idx % 1520;
    int r = rem / 40, c = rem % 40;
    int gy = by + r - 3, gx = bx + c - 4;
    float v = 0.0f;
    if (gy >= 0 && gy < N1 && gx >= 0 && gx < N2)
      v = fmaxf(m[(size_t)(cs * 4 + ch4) * NPIX + (size_t)gy * N2 + gx] * sSc[ch4] + sSh[ch4], 0.0f);
    sIn[ch4][r][c] = v;
  }
  __syncthreads();
  const int ty = tid >> 4, tx = tid & 15;
  float acc00 = 0.f, acc01 = 0.f, acc10 = 0.f, acc11 = 0.f;
#pragma unroll 1
  for (int ch4 = 0; ch4 < 4; ++ch4) {
    float2 wv[8][5];
#pragma unroll
    for (int rr = 0; rr < 8; ++rr)
#pragma unroll
      for (int qq = 0; qq < 5; ++qq)
        wv[rr][qq] = *(const float2*)&sIn[ch4][2 * ty + rr][2 * tx + 2 * qq];
    const float* wch = cw + (cs * 4 + ch4) * 49;   // uniform -> s_load
#pragma unroll
    for (int ky = 0; ky < 7; ++ky)
#pragma unroll
      for (int kx = 0; kx < 7; ++kx) {
        float wt = wch[ky * 7 + kx];
        float e0 = ((kx + 1) & 1) ? wv[ky][(kx + 1) >> 1].y : wv[ky][(kx + 1) >> 1].x;
        float e1 = ((kx + 2) & 1) ? wv[ky][(kx + 2) >> 1].y : wv[ky][(kx + 2) >> 1].x;
        float f0 = ((kx + 1) & 1) ? wv[ky + 1][(kx + 1) >> 1].y : wv[ky + 1][(kx + 1) >> 1].x;
        float f1 = ((kx + 2) & 1) ? wv[ky + 1][(kx + 2) >> 1].y : wv[ky + 1][(kx + 2) >> 1].x;
        acc00 = fmaf(e0, wt, acc00);
        acc01 = fmaf(e1, wt, acc01);
        acc10 = fmaf(f0, wt, acc10);
        acc11 = fmaf(f1, wt, acc11);
      }
  }
  const int oy = by + 2 * ty, ox = bx + 2 * tx;
  float2 r0 = {acc00, acc01}, r1 = {acc10, acc11};
  float* dst = part + (size_t)cs * NPIX;
  *(float2*)&dst[(size_t)oy * N2 + ox] = r0;
  *(float2*)&dst[(size_t)(oy + 1) * N2 + ox] = r1;
}

// ---- sum partials -> BN2 stats (atomic, f32, tiny)
__global__ __launch_bounds__(256) void kE1(const float* __restrict__ part,
                                           float* __restrict__ stats) {
  __shared__ float wred[4][2];
  const int i = blockIdx.x * 256 + threadIdx.x;
  float s = part[i] + part[NPIX + i] + part[2 * NPIX + i] + part[3 * NPIX + i] + part[4 * NPIX + i];
  float q = s * s;
  const int lane = threadIdx.x & 63, wv = threadIdx.x >> 6;
#pragma unroll
  for (int off = 32; off; off >>= 1) {
    s += __shfl_xor(s, off);
    q += __shfl_xor(q, off);
  }
  if (lane == 0) { wred[wv][0] = s; wred[wv][1] = q; }
  __syncthreads();
  if (threadIdx.x < 2) {
    float v = wred[0][threadIdx.x] + wred[1][threadIdx.x] + wred[2][threadIdx.x] + wred[3][threadIdx.x];
    atomicAdd(&stats[2 * HH + threadIdx.x], v);
  }
}

// ---- BN2 + sigmoid -> C (d_out[1:])
__global__ __launch_bounds__(256) void kE2(const float* __restrict__ part,
                                           const float* __restrict__ stats,
                                           const float* __restrict__ bn2g,
                                           const float* __restrict__ bn2b,
                                           float* __restrict__ Cout) {
  const int i = blockIdx.x * 256 + threadIdx.x;
  float s = stats[2 * HH], q = stats[2 * HH + 1];
  float mu = s * (1.0f / NPIX);
  float var = q * (1.0f / NPIX) - mu * mu;
  float g = bn2g[0] / sqrtf(var + 1e-5f);
  float b = bn2b[0] - mu * g;
  float z = (part[i] + part[NPIX + i] + part[2 * NPIX + i] + part[3 * NPIX + i] + part[4 * NPIX + i]) * g + b;
  Cout[i] = 1.0f / (1.0f + expf(-z));
}

// ---- maxpool 9x9 stride 9 pad 4: one wave per window
__global__ __launch_bounds__(256) void kM(const float* __restrict__ C, float* __restrict__ B) {
  const int w = blockIdx.x * 4 + (threadIdx.x >> 6);
  const int lane = threadIdx.x & 63;
  if (w >= PB * PB) return;
  const int wy = w / PB, wx = w % PB;
  const int y0 = wy * 9 - 4, x0 = wx * 9 - 4;
  float mx = -1e30f;
  for (int e = lane; e < 81; e += 64) {
    int y = y0 + e / 9, x = x0 + e % 9;
    if (y >= 0 && y < N1 && x >= 0 && x < N2)
      mx = fmaxf(mx, C[(size_t)y * N2 + x]);
  }
#pragma unroll
  for (int off = 32; off; off >>= 1) mx = fmaxf(mx, __shfl_xor(mx, off));
  if (lane == 0) B[w] = mx;
}

// ---- per-column mean/std(ddof=1), phat -> d_out[0]
__global__ __launch_bounds__(256) void kF(const float* __restrict__ B,
                                          const float* __restrict__ gamma,
                                          float* __restrict__ out0) {
  __shared__ float sB[PB * PB];
  __shared__ float cm[PB], cs[PB];
  __shared__ float r1[4], r2[4];
  const int tid = threadIdx.x;
  for (int i = tid; i < PB * PB; i += 256) sB[i] = B[i];
  __syncthreads();
  if (tid < PB) {
    float s = 0.0f;
    for (int h = 0; h < PB; ++h) s += sB[h * PB + tid];
    float mean = s / (float)PB;
    float v = 0.0f;
    for (int h = 0; h < PB; ++h) { float d = sB[h * PB + tid] - mean; v += d * d; }
    cm[tid] = mean;
    cs[tid] = sqrtf(v / (float)(PB - 1) + 1e-5f);
  }
  __syncthreads();
  const float g = gamma[0];
  float sq = 0.0f, cnt = 0.0f;
  for (int i = tid; i < PB * PB; i += 256) {
    int w = i % PB;
    float qv = sB[i] - cm[w] - g * cs[w];
    if (qv > 0.0f) { sq += qv; cnt += 1.0f; }
  }
#pragma unroll
  for (int off = 32; off; off >>= 1) {
    sq += __shfl_xor(sq, off);
    cnt += __shfl_xor(cnt, off);
  }
  if ((tid & 63) == 0) { r1[tid >> 6] = sq; r2[tid >> 6] = cnt; }
  __syncthreads();
  if (tid == 0) {
    float S = r1[0] + r1[1] + r1[2] + r1[3];
    float Cn = r2[0] + r2[1] + r2[2] + r2[3];
    float phat = S / (Cn + 1.0f);
    float sig = 1.0f / (1.0f + expf(-phat));
    out0[0] = fminf(fmaxf(sig, 0.0f), 1.0f);
  }
}

extern "C" void kernel_launch(void* const* d_in, const int* in_sizes, int n_in,
                              void* d_out, int out_size, void* d_ws, size_t ws_size,
                              hipStream_t stream) {
  const float* x1    = (const float*)d_in[0];
  const float* x2    = (const float*)d_in[1];
  const float* W1    = (const float*)d_in[2];
  const float* b1    = (const float*)d_in[3];
  const float* W2    = (const float*)d_in[4];
  // d_in[5] = b2   : cancels through BN1 (training-mode mean subtraction)
  const float* bn1g  = (const float*)d_in[6];
  const float* bn1b  = (const float*)d_in[7];
  const float* convw = (const float*)d_in[8];
  // d_in[9] = conv_b : cancels through BN2
  const float* bn2g  = (const float*)d_in[10];
  const float* bn2b  = (const float*)d_in[11];
  const float* gamma = (const float*)d_in[12];

  float* ws    = (float*)d_ws;
  float* pp    = ws + WS_PP;
  float* w2t   = ws + WS_W2T;
  float* m     = ws + WS_M;
  float* part  = ws + WS_PART;
  float* stats = ws + WS_STATS;
  float* Bp    = ws + WS_B;
  float* out   = (float*)d_out;

  kW<<<16, 256, 0, stream>>>(W2, w2t, stats);
  kA<<<1024, 256, 0, stream>>>(x1, x2, W1, pp);
  kB<<<512, 256, 0, stream>>>(pp, b1, w2t, m, stats);
  kD<<<dim3(256, 5), 256, 0, stream>>>(m, bn1g, bn1b, convw, stats, part);
  kE1<<<1024, 256, 0, stream>>>(part, stats);
  kE2<<<1024, 256, 0, stream>>>(part, stats, bn2g, bn2b, out + 1);
  kM<<<(PB * PB + 3) / 4, 256, 0, stream>>>(out + 1, Bp);
  kF<<<1, 256, 0, stream>>>(Bp, gamma, out);
}

// Round 5
// 117.397 us; speedup vs baseline: 1.5306x; 1.1834x over previous
//
#include <hip/hip_runtime.h>
#include <hip/hip_bf16.h>
#include <math.h>

#define N1 512
#define N2 512
#define DIN 1280
#define DD 100
#define HH 20
#define NPIX (N1*N2)
#define PB 57

typedef short bf16x8 __attribute__((ext_vector_type(8)));
typedef float f32x4 __attribute__((ext_vector_type(4)));

// workspace layout in floats
static constexpr size_t WS_PP    = 0;                      // 4*1024*100 = 409600
static constexpr size_t WS_W2B   = 409600;                 // 224*32 ushort = 3584 floats -> pad 4096
static constexpr size_t WS_M     = 409600 + 4096;          // 20*512*512 = 5242880
static constexpr size_t WS_PART  = WS_M + 5242880;         // 5*262144 = 1310720
static constexpr size_t WS_STATS = WS_PART + 1310720;      // 64
static constexpr size_t WS_B     = WS_STATS + 64;          // 57*57 = 3249

// ---- build bf16 weight matrix w2b[k][n] = W2[n][k], zero-padded to [224][32]; zero stats
__global__ void kW(const float* __restrict__ W2, unsigned short* __restrict__ w2b,
                   float* __restrict__ stats) {
  int idx = blockIdx.x * 256 + threadIdx.x;
  if (blockIdx.x == 0 && threadIdx.x < 64) stats[threadIdx.x] = 0.0f;
  if (idx >= 224 * 32) return;
  int k = idx >> 5, n = idx & 31;
  float v = (n < HH && k < 200) ? W2[n * 200 + k] : 0.0f;
  __hip_bfloat16 b = __float2bfloat16(v);
  w2b[idx] = *reinterpret_cast<unsigned short*>(&b);
}

// ---- projection partials, 4-way K split: pp[kh][row][h], kh in 0..3 (K=320 each)
__global__ __launch_bounds__(256) void kA(const float* __restrict__ x1,
                                          const float* __restrict__ x2,
                                          const float* __restrict__ W1,
                                          float* __restrict__ pp) {
  const int bi = blockIdx.x >> 2, kh = blockIdx.x & 3;
  const int tid = threadIdx.x;
  const int h = tid & 127;
  const int rq = __builtin_amdgcn_readfirstlane(tid >> 7);  // wave-uniform row group
  const int r0 = bi * 4 + rq * 2;
  const float* xb = (r0 < N1) ? (x1 + (size_t)r0 * DIN) : (x2 + (size_t)(r0 - N1) * DIN);
  if (h >= DD) return;
  const float4* wr  = (const float4*)(W1 + (size_t)h * DIN) + kh * 80;
  const float4* xr0 = (const float4*)xb + kh * 80;
  const float4* xr1 = (const float4*)(xb + DIN) + kh * 80;
  float4 s0 = {0.f, 0.f, 0.f, 0.f}, s1 = {0.f, 0.f, 0.f, 0.f};
  for (int k = 0; k < 80; ++k) {
    float4 w = wr[k], v0 = xr0[k], v1 = xr1[k];
    s0.x = fmaf(w.x, v0.x, s0.x); s0.y = fmaf(w.y, v0.y, s0.y);
    s0.z = fmaf(w.z, v0.z, s0.z); s0.w = fmaf(w.w, v0.w, s0.w);
    s1.x = fmaf(w.x, v1.x, s1.x); s1.y = fmaf(w.y, v1.y, s1.y);
    s1.z = fmaf(w.z, v1.z, s1.z); s1.w = fmaf(w.w, v1.w, s1.w);
  }
  float a0 = (s0.x + s0.y) + (s0.z + s0.w);
  float a1 = (s1.x + s1.y) + (s1.z + s1.w);
  pp[(size_t)kh * 102400 + (size_t)r0 * DD + h] = a0;
  pp[(size_t)kh * 102400 + (size_t)(r0 + 1) * DD + h] = a1;
}

// ---- pairwise features + FC2 via MFMA bf16 + BN1 stats
// block = 16 i-rows x 64 j-cols, 4 waves (one 16-j slice each).
// MFMA: A = W2 (M=h, two 16-row tiles), B = on-the-fly features (N=16 j), K=224.
__global__ __launch_bounds__(256, 1) void kB(const float* __restrict__ pp,
                                             const float* __restrict__ b1,
                                             const unsigned short* __restrict__ w2b,
                                             float* __restrict__ m,
                                             float* __restrict__ stats) {
  __shared__ float sA[16][132];   // a-tile rows, zero-padded cols 100..131
  __shared__ float sC[64][132];   // c-tile rows (132-stride: b128 2-way conflict max)
  __shared__ float wred[4][40];
  const int tid = threadIdx.x;
  const int bi = blockIdx.x >> 3, bj = blockIdx.x & 7;   // 32 i-tiles x 8 j-tiles
  // stage a/c: sum 4 pp partials + b1, float4 path (100 = 25 float4s per row)
  for (int idx = tid; idx < 80 * 33; idx += 256) {
    int r = idx / 33, d4 = idx % 33;
    float4 v = {0.f, 0.f, 0.f, 0.f};
    if (d4 < 25) {
      size_t row = (r < 16) ? (size_t)(bi * 16 + r) : (size_t)(N1 + bj * 64 + (r - 16));
      const float* base = pp + row * DD;
      float4 a0 = ((const float4*)base)[d4];
      float4 a1 = ((const float4*)(base + 102400))[d4];
      float4 a2 = ((const float4*)(base + 204800))[d4];
      float4 a3 = ((const float4*)(base + 307200))[d4];
      float4 bb = ((const float4*)b1)[d4];
      v.x = a0.x + a1.x + a2.x + a3.x + bb.x;
      v.y = a0.y + a1.y + a2.y + a3.y + bb.y;
      v.z = a0.z + a1.z + a2.z + a3.z + bb.z;
      v.w = a0.w + a1.w + a2.w + a3.w + bb.w;
    }
    if (r < 16) *(float4*)&sA[r][4 * d4] = v;
    else        *(float4*)&sC[r - 16][4 * d4] = v;
  }
  __syncthreads();

  const int w    = tid >> 6;
  const int lane = tid & 63;
  const int ln   = lane & 15;    // MFMA n-index: j for features, h for weights
  const int q    = lane >> 4;    // k-quad
  const int jj   = w * 16 + ln;  // this lane's j within tile

  // weight A-frags: lane supplies A[m=ln][k=8q+e] = w2b[k][ln(+16)]
  bf16x8 af[7][2];
#pragma unroll
  for (int ks = 0; ks < 7; ++ks)
#pragma unroll
    for (int t = 0; t < 2; ++t) {
      bf16x8 v;
#pragma unroll
      for (int e = 0; e < 8; ++e)
        v[e] = (short)w2b[(ks * 32 + q * 8 + e) * 32 + ln + 16 * t];
      af[ks][t] = v;
    }

  // per-lane c chunks: half hx covers k = 32*(hx>>1) + 8q + 4*(hx&1) .. +3
  // k<100 -> diff at d=k ; k in [100,200) -> prod at d=k-100 ; k>=200 -> prod vs zero-pad
  int dOf[14];
  bool isP[14];
  float4 cH[14];
#pragma unroll
  for (int hx = 0; hx < 14; ++hx) {
    int kh = (hx >> 1) * 32 + q * 8 + (hx & 1) * 4;
    bool p = kh >= 100;
    isP[hx] = p;
    int d = p ? kh - 100 : kh;
    dOf[hx] = d;
    cH[hx] = *(const float4*)&sC[jj][d];
  }

  float st_s[8], st_q[8];
#pragma unroll
  for (int r = 0; r < 8; ++r) { st_s[r] = 0.f; st_q[r] = 0.f; }

  const int gj = bj * 64 + jj;
#pragma unroll 1
  for (int ii = 0; ii < 16; ++ii) {
    bf16x8 bf[7];
#pragma unroll
    for (int ks = 0; ks < 7; ++ks) {
      float4 a0 = *(const float4*)&sA[ii][dOf[2 * ks]];      // 16-lane broadcast reads
      float4 a1 = *(const float4*)&sA[ii][dOf[2 * ks + 1]];
      float4 c0 = cH[2 * ks], c1 = cH[2 * ks + 1];
      float f0 = isP[2*ks]   ? a0.x * c0.x : fabsf(a0.x - c0.x);
      float f1 = isP[2*ks]   ? a0.y * c0.y : fabsf(a0.y - c0.y);
      float f2 = isP[2*ks]   ? a0.z * c0.z : fabsf(a0.z - c0.z);
      float f3 = isP[2*ks]   ? a0.w * c0.w : fabsf(a0.w - c0.w);
      float f4 = isP[2*ks+1] ? a1.x * c1.x : fabsf(a1.x - c1.x);
      float f5 = isP[2*ks+1] ? a1.y * c1.y : fabsf(a1.y - c1.y);
      float f6 = isP[2*ks+1] ? a1.z * c1.z : fabsf(a1.z - c1.z);
      float f7 = isP[2*ks+1] ? a1.w * c1.w : fabsf(a1.w - c1.w);
      union { bf16x8 v; __hip_bfloat162 h2[4]; } u;
      u.h2[0] = __float22bfloat162_rn(make_float2(f0, f1));
      u.h2[1] = __float22bfloat162_rn(make_float2(f2, f3));
      u.h2[2] = __float22bfloat162_rn(make_float2(f4, f5));
      u.h2[3] = __float22bfloat162_rn(make_float2(f6, f7));
      bf[ks] = u.v;
    }
    f32x4 acc0 = {0.f, 0.f, 0.f, 0.f}, acc1 = {0.f, 0.f, 0.f, 0.f};
#pragma unroll
    for (int ks = 0; ks < 7; ++ks) {
      acc0 = __builtin_amdgcn_mfma_f32_16x16x32_bf16(af[ks][0], bf[ks], acc0, 0, 0, 0);
      acc1 = __builtin_amdgcn_mfma_f32_16x16x32_bf16(af[ks][1], bf[ks], acc1, 0, 0, 0);
    }
    // D: row h = 4q+r (+16 for tile1), col j = ln  [verified m89 C/D mapping]
    const size_t pix = (size_t)(bi * 16 + ii) * N2 + gj;
#pragma unroll
    for (int r = 0; r < 4; ++r) {
      m[(size_t)(4 * q + r) * NPIX + pix] = acc0[r];
      st_s[r] += acc0[r];
      st_q[r] += acc0[r] * acc0[r];
    }
    if (q == 0) {
#pragma unroll
      for (int r = 0; r < 4; ++r)
        m[(size_t)(16 + r) * NPIX + pix] = acc1[r];
    }
#pragma unroll
    for (int r = 0; r < 4; ++r) {       // rows h>=20 are exact zeros (A zero-padded)
      st_s[4 + r] += acc1[r];
      st_q[4 + r] += acc1[r] * acc1[r];
    }
  }
  // reduce stats over each 16-lane j-group
#pragma unroll
  for (int r = 0; r < 8; ++r) {
#pragma unroll
    for (int off = 1; off < 16; off <<= 1) {
      st_s[r] += __shfl_xor(st_s[r], off);
      st_q[r] += __shfl_xor(st_q[r], off);
    }
  }
  if (ln == 0) {
#pragma unroll
    for (int r = 0; r < 4; ++r) {
      wred[w][4 * q + r]      = st_s[r];
      wred[w][20 + 4 * q + r] = st_q[r];
    }
    if (q == 0) {
#pragma unroll
      for (int r = 0; r < 4; ++r) {
        wred[w][16 + r] = st_s[4 + r];
        wred[w][36 + r] = st_q[4 + r];
      }
    }
  }
  __syncthreads();
  if (tid < 40) {
    float s = wred[0][tid] + wred[1][tid] + wred[2][tid] + wred[3][tid];
    atomicAdd(&stats[tid], s);
  }
}

// ---- conv 7x7, 4 channels per block (5-way split), BN1+relu at staging
__global__ __launch_bounds__(256, 4) void kD(const float* __restrict__ m,
                                             const float* __restrict__ bn1g,
                                             const float* __restrict__ bn1b,
                                             const float* __restrict__ cw,
                                             const float* __restrict__ stats,
                                             float* __restrict__ part) {
  __shared__ float sIn[4][38][40];
  __shared__ float sSc[4], sSh[4];
  const int tid = threadIdx.x;
  const int cs = blockIdx.y;               // channel chunk 0..4
  if (tid < 4) {
    int ch = cs * 4 + tid;
    float s = stats[ch], q = stats[HH + ch];
    float mu = s * (1.0f / NPIX);
    float var = q * (1.0f / NPIX) - mu * mu;
    float g = bn1g[ch] / sqrtf(var + 1e-5f);
    sSc[tid] = g;
    sSh[tid] = bn1b[ch] - mu * g;
  }
  __syncthreads();
  const int by = (blockIdx.x >> 4) * 32, bx = (blockIdx.x & 15) * 32;
  for (int idx = tid; idx < 4 * 38 * 40; idx += 256) {
    int ch4 = idx / 1520, rem = idx % 1520;
    int r = rem / 40, c = rem % 40;
    int gy = by + r - 3, gx = bx + c - 4;
    float v = 0.0f;
    if (gy >= 0 && gy < N1 && gx >= 0 && gx < N2)
      v = fmaxf(m[(size_t)(cs * 4 + ch4) * NPIX + (size_t)gy * N2 + gx] * sSc[ch4] + sSh[ch4], 0.0f);
    sIn[ch4][r][c] = v;
  }
  __syncthreads();
  const int ty = tid >> 4, tx = tid & 15;
  float acc00 = 0.f, acc01 = 0.f, acc10 = 0.f, acc11 = 0.f;
#pragma unroll 1
  for (int ch4 = 0; ch4 < 4; ++ch4) {
    float2 wv[8][5];
#pragma unroll
    for (int rr = 0; rr < 8; ++rr)
#pragma unroll
      for (int qq = 0; qq < 5; ++qq)
        wv[rr][qq] = *(const float2*)&sIn[ch4][2 * ty + rr][2 * tx + 2 * qq];
    const float* wch = cw + (cs * 4 + ch4) * 49;   // uniform -> s_load
#pragma unroll
    for (int ky = 0; ky < 7; ++ky)
#pragma unroll
      for (int kx = 0; kx < 7; ++kx) {
        float wt = wch[ky * 7 + kx];
        float e0 = ((kx + 1) & 1) ? wv[ky][(kx + 1) >> 1].y : wv[ky][(kx + 1) >> 1].x;
        float e1 = ((kx + 2) & 1) ? wv[ky][(kx + 2) >> 1].y : wv[ky][(kx + 2) >> 1].x;
        float f0 = ((kx + 1) & 1) ? wv[ky + 1][(kx + 1) >> 1].y : wv[ky + 1][(kx + 1) >> 1].x;
        float f1 = ((kx + 2) & 1) ? wv[ky + 1][(kx + 2) >> 1].y : wv[ky + 1][(kx + 2) >> 1].x;
        acc00 = fmaf(e0, wt, acc00);
        acc01 = fmaf(e1, wt, acc01);
        acc10 = fmaf(f0, wt, acc10);
        acc11 = fmaf(f1, wt, acc11);
      }
  }
  const int oy = by + 2 * ty, ox = bx + 2 * tx;
  float2 r0 = {acc00, acc01}, r1 = {acc10, acc11};
  float* dst = part + (size_t)cs * NPIX;
  *(float2*)&dst[(size_t)oy * N2 + ox] = r0;
  *(float2*)&dst[(size_t)(oy + 1) * N2 + ox] = r1;
}

// ---- sum partials -> BN2 stats (atomic, f32, tiny)
__global__ __launch_bounds__(256) void kE1(const float* __restrict__ part,
                                           float* __restrict__ stats) {
  __shared__ float wred[4][2];
  const int i = blockIdx.x * 256 + threadIdx.x;
  float s = part[i] + part[NPIX + i] + part[2 * NPIX + i] + part[3 * NPIX + i] + part[4 * NPIX + i];
  float q = s * s;
  const int lane = threadIdx.x & 63, wv = threadIdx.x >> 6;
#pragma unroll
  for (int off = 32; off; off >>= 1) {
    s += __shfl_xor(s, off);
    q += __shfl_xor(q, off);
  }
  if (lane == 0) { wred[wv][0] = s; wred[wv][1] = q; }
  __syncthreads();
  if (threadIdx.x < 2) {
    float v = wred[0][threadIdx.x] + wred[1][threadIdx.x] + wred[2][threadIdx.x] + wred[3][threadIdx.x];
    atomicAdd(&stats[2 * HH + threadIdx.x], v);
  }
}

// ---- BN2 + sigmoid -> C (d_out[1:])
__global__ __launch_bounds__(256) void kE2(const float* __restrict__ part,
                                           const float* __restrict__ stats,
                                           const float* __restrict__ bn2g,
                                           const float* __restrict__ bn2b,
                                           float* __restrict__ Cout) {
  const int i = blockIdx.x * 256 + threadIdx.x;
  float s = stats[2 * HH], q = stats[2 * HH + 1];
  float mu = s * (1.0f / NPIX);
  float var = q * (1.0f / NPIX) - mu * mu;
  float g = bn2g[0] / sqrtf(var + 1e-5f);
  float b = bn2b[0] - mu * g;
  float z = (part[i] + part[NPIX + i] + part[2 * NPIX + i] + part[3 * NPIX + i] + part[4 * NPIX + i]) * g + b;
  Cout[i] = 1.0f / (1.0f + expf(-z));
}

// ---- maxpool 9x9 stride 9 pad 4: one wave per window
__global__ __launch_bounds__(256) void kM(const float* __restrict__ C, float* __restrict__ B) {
  const int w = blockIdx.x * 4 + (threadIdx.x >> 6);
  const int lane = threadIdx.x & 63;
  if (w >= PB * PB) return;
  const int wy = w / PB, wx = w % PB;
  const int y0 = wy * 9 - 4, x0 = wx * 9 - 4;
  float mx = -1e30f;
  for (int e = lane; e < 81; e += 64) {
    int y = y0 + e / 9, x = x0 + e % 9;
    if (y >= 0 && y < N1 && x >= 0 && x < N2)
      mx = fmaxf(mx, C[(size_t)y * N2 + x]);
  }
#pragma unroll
  for (int off = 32; off; off >>= 1) mx = fmaxf(mx, __shfl_xor(mx, off));
  if (lane == 0) B[w] = mx;
}

// ---- per-column mean/std(ddof=1), phat -> d_out[0]
__global__ __launch_bounds__(256) void kF(const float* __restrict__ B,
                                          const float* __restrict__ gamma,
                                          float* __restrict__ out0) {
  __shared__ float sB[PB * PB];
  __shared__ float cm[PB], cs[PB];
  __shared__ float r1[4], r2[4];
  const int tid = threadIdx.x;
  for (int i = tid; i < PB * PB; i += 256) sB[i] = B[i];
  __syncthreads();
  if (tid < PB) {
    float s = 0.0f;
    for (int h = 0; h < PB; ++h) s += sB[h * PB + tid];
    float mean = s / (float)PB;
    float v = 0.0f;
    for (int h = 0; h < PB; ++h) { float d = sB[h * PB + tid] - mean; v += d * d; }
    cm[tid] = mean;
    cs[tid] = sqrtf(v / (float)(PB - 1) + 1e-5f);
  }
  __syncthreads();
  const float g = gamma[0];
  float sq = 0.0f, cnt = 0.0f;
  for (int i = tid; i < PB * PB; i += 256) {
    int w = i % PB;
    float qv = sB[i] - cm[w] - g * cs[w];
    if (qv > 0.0f) { sq += qv; cnt += 1.0f; }
  }
#pragma unroll
  for (int off = 32; off; off >>= 1) {
    sq += __shfl_xor(sq, off);
    cnt += __shfl_xor(cnt, off);
  }
  if ((tid & 63) == 0) { r1[tid >> 6] = sq; r2[tid >> 6] = cnt; }
  __syncthreads();
  if (tid == 0) {
    float S = r1[0] + r1[1] + r1[2] + r1[3];
    float Cn = r2[0] + r2[1] + r2[2] + r2[3];
    float phat = S / (Cn + 1.0f);
    float sig = 1.0f / (1.0f + expf(-phat));
    out0[0] = fminf(fmaxf(sig, 0.0f), 1.0f);
  }
}

extern "C" void kernel_launch(void* const* d_in, const int* in_sizes, int n_in,
                              void* d_out, int out_size, void* d_ws, size_t ws_size,
                              hipStream_t stream) {
  const float* x1    = (const float*)d_in[0];
  const float* x2    = (const float*)d_in[1];
  const float* W1    = (const float*)d_in[2];
  const float* b1    = (const float*)d_in[3];
  const float* W2    = (const float*)d_in[4];
  // d_in[5] = b2   : cancels through BN1 (training-mode mean subtraction)
  const float* bn1g  = (const float*)d_in[6];
  const float* bn1b  = (const float*)d_in[7];
  const float* convw = (const float*)d_in[8];
  // d_in[9] = conv_b : cancels through BN2
  const float* bn2g  = (const float*)d_in[10];
  const float* bn2b  = (const float*)d_in[11];
  const float* gamma = (const float*)d_in[12];

  float* ws    = (float*)d_ws;
  float* pp    = ws + WS_PP;
  unsigned short* w2b = (unsigned short*)(ws + WS_W2B);
  float* m     = ws + WS_M;
  float* part  = ws + WS_PART;
  float* stats = ws + WS_STATS;
  float* Bp    = ws + WS_B;
  float* out   = (float*)d_out;

  kW<<<28, 256, 0, stream>>>(W2, w2b, stats);
  kA<<<1024, 256, 0, stream>>>(x1, x2, W1, pp);
  kB<<<256, 256, 0, stream>>>(pp, b1, w2b, m, stats);
  kD<<<dim3(256, 5), 256, 0, stream>>>(m, bn1g, bn1b, convw, stats, part);
  kE1<<<1024, 256, 0, stream>>>(part, stats);
  kE2<<<1024, 256, 0, stream>>>(part, stats, bn2g, bn2b, out + 1);
  kM<<<(PB * PB + 3) / 4, 256, 0, stream>>>(out + 1, Bp);
  kF<<<1, 256, 0, stream>>>(Bp, gamma, out);
}

// Round 6
// 116.673 us; speedup vs baseline: 1.5400x; 1.0062x over previous
//
#include <hip/hip_runtime.h>
#include <hip/hip_bf16.h>
#include <math.h>

#define N1 512
#define N2 512
#define DIN 1280
#define DD 100
#define HH 20
#define NPIX (N1*N2)
#define PB 57

typedef short bf16x8 __attribute__((ext_vector_type(8)));
typedef float f32x4 __attribute__((ext_vector_type(4)));

// workspace layout in floats
static constexpr size_t WS_PP    = 0;                      // 4*1024*100 = 409600
static constexpr size_t WS_W2B   = 409600;                 // 224*32 ushort -> pad 4096
static constexpr size_t WS_M     = 413696;                 // 20*512*512 = 5242880
static constexpr size_t WS_PART  = WS_M + 5242880;         // 5*262144 = 1310720
static constexpr size_t WS_CRAW  = WS_PART + 1310720;      // 262144
static constexpr size_t WS_STATS = WS_CRAW + 262144;       // 64
static constexpr size_t WS_B     = WS_STATS + 64;          // 57*57 = 3249

// ---- projection partials (4-way K split) + folded-in W2 repack / stats zero
__global__ __launch_bounds__(256) void kA(const float* __restrict__ x1,
                                          const float* __restrict__ x2,
                                          const float* __restrict__ W1,
                                          const float* __restrict__ W2,
                                          float* __restrict__ pp,
                                          unsigned short* __restrict__ w2b,
                                          float* __restrict__ stats) {
  if (blockIdx.x >= 1024) {   // kW work: build bf16 W2^T [224][32] + zero stats
    int idx = (blockIdx.x - 1024) * 256 + threadIdx.x;
    if (blockIdx.x == 1024 && threadIdx.x < 64) stats[threadIdx.x] = 0.0f;
    if (idx < 224 * 32) {
      int k = idx >> 5, n = idx & 31;
      float v = (n < HH && k < 200) ? W2[n * 200 + k] : 0.0f;
      __hip_bfloat16 b = __float2bfloat16(v);
      w2b[idx] = *reinterpret_cast<unsigned short*>(&b);
    }
    return;
  }
  const int bi = blockIdx.x >> 2, kh = blockIdx.x & 3;
  const int tid = threadIdx.x;
  const int h = tid & 127;
  const int rq = __builtin_amdgcn_readfirstlane(tid >> 7);  // wave-uniform row group
  const int r0 = bi * 4 + rq * 2;
  const float* xb = (r0 < N1) ? (x1 + (size_t)r0 * DIN) : (x2 + (size_t)(r0 - N1) * DIN);
  if (h >= DD) return;
  const float4* wr  = (const float4*)(W1 + (size_t)h * DIN) + kh * 80;
  const float4* xr0 = (const float4*)xb + kh * 80;
  const float4* xr1 = (const float4*)(xb + DIN) + kh * 80;
  float4 s0 = {0.f, 0.f, 0.f, 0.f}, s1 = {0.f, 0.f, 0.f, 0.f};
  for (int k = 0; k < 80; ++k) {
    float4 w = wr[k], v0 = xr0[k], v1 = xr1[k];
    s0.x = fmaf(w.x, v0.x, s0.x); s0.y = fmaf(w.y, v0.y, s0.y);
    s0.z = fmaf(w.z, v0.z, s0.z); s0.w = fmaf(w.w, v0.w, s0.w);
    s1.x = fmaf(w.x, v1.x, s1.x); s1.y = fmaf(w.y, v1.y, s1.y);
    s1.z = fmaf(w.z, v1.z, s1.z); s1.w = fmaf(w.w, v1.w, s1.w);
  }
  float a0 = (s0.x + s0.y) + (s0.z + s0.w);
  float a1 = (s1.x + s1.y) + (s1.z + s1.w);
  pp[(size_t)kh * 102400 + (size_t)r0 * DD + h] = a0;
  pp[(size_t)kh * 102400 + (size_t)(r0 + 1) * DD + h] = a1;
}

// ---- pairwise features + FC2 via MFMA bf16 + BN1 stats
// block = 16 i-rows x 32 j-cols, 2 waves (one 16-j slice each); grid 32x16 = 512.
__global__ __launch_bounds__(128, 2) void kB(const float* __restrict__ pp,
                                             const float* __restrict__ b1,
                                             const unsigned short* __restrict__ w2b,
                                             float* __restrict__ m,
                                             float* __restrict__ stats) {
  __shared__ float sA[16][132];   // a-rows, zero-padded cols 100..131
  __shared__ float sC[32][132];
  __shared__ float wred[2][40];
  const int tid = threadIdx.x;
  const int bi = blockIdx.x >> 4, bj = blockIdx.x & 15;   // 32 i-tiles x 16 j-tiles
  for (int idx = tid; idx < 48 * 33; idx += 128) {
    int r = idx / 33, d4 = idx % 33;
    float4 v = {0.f, 0.f, 0.f, 0.f};
    if (d4 < 25) {
      size_t row = (r < 16) ? (size_t)(bi * 16 + r) : (size_t)(N1 + bj * 32 + (r - 16));
      const float* base = pp + row * DD;
      float4 a0 = ((const float4*)base)[d4];
      float4 a1 = ((const float4*)(base + 102400))[d4];
      float4 a2 = ((const float4*)(base + 204800))[d4];
      float4 a3 = ((const float4*)(base + 307200))[d4];
      float4 bb = ((const float4*)b1)[d4];
      v.x = a0.x + a1.x + a2.x + a3.x + bb.x;
      v.y = a0.y + a1.y + a2.y + a3.y + bb.y;
      v.z = a0.z + a1.z + a2.z + a3.z + bb.z;
      v.w = a0.w + a1.w + a2.w + a3.w + bb.w;
    }
    if (r < 16) *(float4*)&sA[r][4 * d4] = v;
    else        *(float4*)&sC[r - 16][4 * d4] = v;
  }
  __syncthreads();

  const int w    = tid >> 6;     // wave 0..1
  const int lane = tid & 63;
  const int ln   = lane & 15;    // MFMA n-index
  const int q    = lane >> 4;    // k-quad
  const int jj   = w * 16 + ln;  // j within 32-tile

  // weight A-frags: lane supplies A[m=ln][k=8q+e] = w2b[k][ln(+16)]
  bf16x8 af[7][2];
#pragma unroll
  for (int ks = 0; ks < 7; ++ks)
#pragma unroll
    for (int t = 0; t < 2; ++t) {
      bf16x8 v;
#pragma unroll
      for (int e = 0; e < 8; ++e)
        v[e] = (short)w2b[(ks * 32 + q * 8 + e) * 32 + ln + 16 * t];
      af[ks][t] = v;
    }

  // per-lane c chunks: half hx covers k = 32*(hx>>1) + 8q + 4*(hx&1)
  int dOf[14];
  bool isP[14];
  float4 cH[14];
#pragma unroll
  for (int hx = 0; hx < 14; ++hx) {
    int kh = (hx >> 1) * 32 + q * 8 + (hx & 1) * 4;
    bool p = kh >= 100;
    isP[hx] = p;
    int d = p ? kh - 100 : kh;
    dOf[hx] = d;
    cH[hx] = *(const float4*)&sC[jj][d];
  }

  float st_s[8], st_q[8];
#pragma unroll
  for (int r = 0; r < 8; ++r) { st_s[r] = 0.f; st_q[r] = 0.f; }

  const int gj = bj * 32 + jj;
#pragma unroll 1
  for (int ii = 0; ii < 16; ++ii) {
    bf16x8 bf[7];
#pragma unroll
    for (int ks = 0; ks < 7; ++ks) {
      float4 a0 = *(const float4*)&sA[ii][dOf[2 * ks]];      // 16-lane broadcast reads
      float4 a1 = *(const float4*)&sA[ii][dOf[2 * ks + 1]];
      float4 c0 = cH[2 * ks], c1 = cH[2 * ks + 1];
      float f0 = isP[2*ks]   ? a0.x * c0.x : fabsf(a0.x - c0.x);
      float f1 = isP[2*ks]   ? a0.y * c0.y : fabsf(a0.y - c0.y);
      float f2 = isP[2*ks]   ? a0.z * c0.z : fabsf(a0.z - c0.z);
      float f3 = isP[2*ks]   ? a0.w * c0.w : fabsf(a0.w - c0.w);
      float f4 = isP[2*ks+1] ? a1.x * c1.x : fabsf(a1.x - c1.x);
      float f5 = isP[2*ks+1] ? a1.y * c1.y : fabsf(a1.y - c1.y);
      float f6 = isP[2*ks+1] ? a1.z * c1.z : fabsf(a1.z - c1.z);
      float f7 = isP[2*ks+1] ? a1.w * c1.w : fabsf(a1.w - c1.w);
      union { bf16x8 v; __hip_bfloat162 h2[4]; } u;
      u.h2[0] = __float22bfloat162_rn(make_float2(f0, f1));
      u.h2[1] = __float22bfloat162_rn(make_float2(f2, f3));
      u.h2[2] = __float22bfloat162_rn(make_float2(f4, f5));
      u.h2[3] = __float22bfloat162_rn(make_float2(f6, f7));
      bf[ks] = u.v;
    }
    f32x4 acc0 = {0.f, 0.f, 0.f, 0.f}, acc1 = {0.f, 0.f, 0.f, 0.f};
#pragma unroll
    for (int ks = 0; ks < 7; ++ks) {
      acc0 = __builtin_amdgcn_mfma_f32_16x16x32_bf16(af[ks][0], bf[ks], acc0, 0, 0, 0);
      acc1 = __builtin_amdgcn_mfma_f32_16x16x32_bf16(af[ks][1], bf[ks], acc1, 0, 0, 0);
    }
    // D: row h = 4q+r (+16 tile1), col j = ln  [verified m89 C/D mapping]
    const size_t pix = (size_t)(bi * 16 + ii) * N2 + gj;
#pragma unroll
    for (int r = 0; r < 4; ++r) {
      m[(size_t)(4 * q + r) * NPIX + pix] = acc0[r];
      st_s[r] += acc0[r];
      st_q[r] += acc0[r] * acc0[r];
    }
    if (q == 0) {
#pragma unroll
      for (int r = 0; r < 4; ++r)
        m[(size_t)(16 + r) * NPIX + pix] = acc1[r];
    }
#pragma unroll
    for (int r = 0; r < 4; ++r) {       // rows h>=20 are exact zeros
      st_s[4 + r] += acc1[r];
      st_q[4 + r] += acc1[r] * acc1[r];
    }
  }
#pragma unroll
  for (int r = 0; r < 8; ++r) {
#pragma unroll
    for (int off = 1; off < 16; off <<= 1) {
      st_s[r] += __shfl_xor(st_s[r], off);
      st_q[r] += __shfl_xor(st_q[r], off);
    }
  }
  if (ln == 0) {
#pragma unroll
    for (int r = 0; r < 4; ++r) {
      wred[w][4 * q + r]      = st_s[r];
      wred[w][20 + 4 * q + r] = st_q[r];
    }
    if (q == 0) {
#pragma unroll
      for (int r = 0; r < 4; ++r) {
        wred[w][16 + r] = st_s[4 + r];
        wred[w][36 + r] = st_q[4 + r];
      }
    }
  }
  __syncthreads();
  if (tid < 40) atomicAdd(&stats[tid], wred[0][tid] + wred[1][tid]);
}

// ---- conv 7x7, 4 channels per block (5-way split), BN1+relu at staging
__global__ __launch_bounds__(256, 4) void kD(const float* __restrict__ m,
                                             const float* __restrict__ bn1g,
                                             const float* __restrict__ bn1b,
                                             const float* __restrict__ cw,
                                             const float* __restrict__ stats,
                                             float* __restrict__ part) {
  __shared__ float sIn[4][38][40];
  __shared__ float sSc[4], sSh[4];
  const int tid = threadIdx.x;
  const int cs = blockIdx.y;               // channel chunk 0..4
  if (tid < 4) {
    int ch = cs * 4 + tid;
    float s = stats[ch], q = stats[HH + ch];
    float mu = s * (1.0f / NPIX);
    float var = q * (1.0f / NPIX) - mu * mu;
    float g = bn1g[ch] / sqrtf(var + 1e-5f);
    sSc[tid] = g;
    sSh[tid] = bn1b[ch] - mu * g;
  }
  __syncthreads();
  const int by = (blockIdx.x >> 4) * 32, bx = (blockIdx.x & 15) * 32;
  for (int idx = tid; idx < 4 * 38 * 40; idx += 256) {
    int ch4 = idx / 1520, rem = idx % 1520;
    int r = rem / 40, c = rem % 40;
    int gy = by + r - 3, gx = bx + c - 4;
    float v = 0.0f;
    if (gy >= 0 && gy < N1 && gx >= 0 && gx < N2)
      v = fmaxf(m[(size_t)(cs * 4 + ch4) * NPIX + (size_t)gy * N2 + gx] * sSc[ch4] + sSh[ch4], 0.0f);
    sIn[ch4][r][c] = v;
  }
  __syncthreads();
  const int ty = tid >> 4, tx = tid & 15;
  float acc00 = 0.f, acc01 = 0.f, acc10 = 0.f, acc11 = 0.f;
#pragma unroll 1
  for (int ch4 = 0; ch4 < 4; ++ch4) {
    float2 wv[8][5];
#pragma unroll
    for (int rr = 0; rr < 8; ++rr)
#pragma unroll
      for (int qq = 0; qq < 5; ++qq)
        wv[rr][qq] = *(const float2*)&sIn[ch4][2 * ty + rr][2 * tx + 2 * qq];
    const float* wch = cw + (cs * 4 + ch4) * 49;   // uniform -> s_load
#pragma unroll
    for (int ky = 0; ky < 7; ++ky)
#pragma unroll
      for (int kx = 0; kx < 7; ++kx) {
        float wt = wch[ky * 7 + kx];
        float e0 = ((kx + 1) & 1) ? wv[ky][(kx + 1) >> 1].y : wv[ky][(kx + 1) >> 1].x;
        float e1 = ((kx + 2) & 1) ? wv[ky][(kx + 2) >> 1].y : wv[ky][(kx + 2) >> 1].x;
        float f0 = ((kx + 1) & 1) ? wv[ky + 1][(kx + 1) >> 1].y : wv[ky + 1][(kx + 1) >> 1].x;
        float f1 = ((kx + 2) & 1) ? wv[ky + 1][(kx + 2) >> 1].y : wv[ky + 1][(kx + 2) >> 1].x;
        acc00 = fmaf(e0, wt, acc00);
        acc01 = fmaf(e1, wt, acc01);
        acc10 = fmaf(f0, wt, acc10);
        acc11 = fmaf(f1, wt, acc11);
      }
  }
  const int oy = by + 2 * ty, ox = bx + 2 * tx;
  float2 r0 = {acc00, acc01}, r1 = {acc10, acc11};
  float* dst = part + (size_t)cs * NPIX;
  *(float2*)&dst[(size_t)oy * N2 + ox] = r0;
  *(float2*)&dst[(size_t)(oy + 1) * N2 + ox] = r1;
}

// ---- sum partials -> Craw + BN2 stats
__global__ __launch_bounds__(256) void kE1(const float* __restrict__ part,
                                           float* __restrict__ stats,
                                           float* __restrict__ Craw) {
  __shared__ float wred[4][2];
  const int i = blockIdx.x * 256 + threadIdx.x;
  float s5 = part[i] + part[NPIX + i] + part[2 * NPIX + i] + part[3 * NPIX + i] + part[4 * NPIX + i];
  Craw[i] = s5;
  float s = s5, q = s5 * s5;
  const int lane = threadIdx.x & 63, wv = threadIdx.x >> 6;
#pragma unroll
  for (int off = 32; off; off >>= 1) {
    s += __shfl_xor(s, off);
    q += __shfl_xor(q, off);
  }
  if (lane == 0) { wred[wv][0] = s; wred[wv][1] = q; }
  __syncthreads();
  if (threadIdx.x < 2) {
    float v = wred[0][threadIdx.x] + wred[1][threadIdx.x] + wred[2][threadIdx.x] + wred[3][threadIdx.x];
    atomicAdd(&stats[2 * HH + threadIdx.x], v);
  }
}

// ---- fused BN2 + sigmoid + maxpool: one wave per 9x9 window (windows partition the grid;
//      edge windows also claim the 509..511 L-strip for the Cout write)
__global__ __launch_bounds__(256) void kE2M(const float* __restrict__ Craw,
                                            const float* __restrict__ stats,
                                            const float* __restrict__ bn2g,
                                            const float* __restrict__ bn2b,
                                            float* __restrict__ Cout,
                                            float* __restrict__ B) {
  const int w = blockIdx.x * 4 + (threadIdx.x >> 6);
  const int lane = threadIdx.x & 63;
  float s = stats[2 * HH], q = stats[2 * HH + 1];
  float mu = s * (1.0f / NPIX);
  float var = q * (1.0f / NPIX) - mu * mu;
  float g = bn2g[0] / sqrtf(var + 1e-5f);
  float b = bn2b[0] - mu * g;
  if (w >= PB * PB) return;
  const int wy = w / PB, wx = w % PB;
  const int y0 = wy * 9 - 4, x0 = wx * 9 - 4;
  float mx = -1e30f;
  for (int e = lane; e < 144; e += 64) {
    int dy = e / 12, dx = e % 12;
    int y = y0 + dy, x = x0 + dx;
    bool inWin = (dy < 9) && (dx < 9);
    bool claim = (y >= 0) && (y < N1) && (x >= 0) && (x < N2) &&
                 (dy < 9 || wy == PB - 1) && (dx < 9 || wx == PB - 1);
    if (claim) {
      float z = Craw[(size_t)y * N2 + x] * g + b;
      float sg = 1.0f / (1.0f + expf(-z));
      Cout[(size_t)y * N2 + x] = sg;
      if (inWin) mx = fmaxf(mx, sg);
    }
  }
#pragma unroll
  for (int off = 32; off; off >>= 1) mx = fmaxf(mx, __shfl_xor(mx, off));
  if (lane == 0) B[w] = mx;
}

// ---- per-column mean/std(ddof=1), phat -> d_out[0]
__global__ __launch_bounds__(256) void kF(const float* __restrict__ B,
                                          const float* __restrict__ gamma,
                                          float* __restrict__ out0) {
  __shared__ float sB[PB * PB];
  __shared__ float cm[PB], cs[PB];
  __shared__ float r1[4], r2[4];
  const int tid = threadIdx.x;
  for (int i = tid; i < PB * PB; i += 256) sB[i] = B[i];
  __syncthreads();
  if (tid < PB) {
    float s = 0.0f;
    for (int h = 0; h < PB; ++h) s += sB[h * PB + tid];
    float mean = s / (float)PB;
    float v = 0.0f;
    for (int h = 0; h < PB; ++h) { float d = sB[h * PB + tid] - mean; v += d * d; }
    cm[tid] = mean;
    cs[tid] = sqrtf(v / (float)(PB - 1) + 1e-5f);
  }
  __syncthreads();
  const float g = gamma[0];
  float sq = 0.0f, cnt = 0.0f;
  for (int i = tid; i < PB * PB; i += 256) {
    int w = i % PB;
    float qv = sB[i] - cm[w] - g * cs[w];
    if (qv > 0.0f) { sq += qv; cnt += 1.0f; }
  }
#pragma unroll
  for (int off = 32; off; off >>= 1) {
    sq += __shfl_xor(sq, off);
    cnt += __shfl_xor(cnt, off);
  }
  if ((tid & 63) == 0) { r1[tid >> 6] = sq; r2[tid >> 6] = cnt; }
  __syncthreads();
  if (tid == 0) {
    float S = r1[0] + r1[1] + r1[2] + r1[3];
    float Cn = r2[0] + r2[1] + r2[2] + r2[3];
    float phat = S / (Cn + 1.0f);
    float sig = 1.0f / (1.0f + expf(-phat));
    out0[0] = fminf(fmaxf(sig, 0.0f), 1.0f);
  }
}

extern "C" void kernel_launch(void* const* d_in, const int* in_sizes, int n_in,
                              void* d_out, int out_size, void* d_ws, size_t ws_size,
                              hipStream_t stream) {
  const float* x1    = (const float*)d_in[0];
  const float* x2    = (const float*)d_in[1];
  const float* W1    = (const float*)d_in[2];
  const float* b1    = (const float*)d_in[3];
  const float* W2    = (const float*)d_in[4];
  // d_in[5] = b2   : cancels through BN1 (training-mode mean subtraction)
  const float* bn1g  = (const float*)d_in[6];
  const float* bn1b  = (const float*)d_in[7];
  const float* convw = (const float*)d_in[8];
  // d_in[9] = conv_b : cancels through BN2
  const float* bn2g  = (const float*)d_in[10];
  const float* bn2b  = (const float*)d_in[11];
  const float* gamma = (const float*)d_in[12];

  float* ws    = (float*)d_ws;
  float* pp    = ws + WS_PP;
  unsigned short* w2b = (unsigned short*)(ws + WS_W2B);
  float* m     = ws + WS_M;
  float* part  = ws + WS_PART;
  float* Craw  = ws + WS_CRAW;
  float* stats = ws + WS_STATS;
  float* Bp    = ws + WS_B;
  float* out   = (float*)d_out;

  kA<<<1052, 256, 0, stream>>>(x1, x2, W1, W2, pp, w2b, stats);
  kB<<<512, 128, 0, stream>>>(pp, b1, w2b, m, stats);
  kD<<<dim3(256, 5), 256, 0, stream>>>(m, bn1g, bn1b, convw, stats, part);
  kE1<<<1024, 256, 0, stream>>>(part, stats, Craw);
  kE2M<<<(PB * PB + 3) / 4, 256, 0, stream>>>(Craw, stats, bn2g, bn2b, out + 1, Bp);
  kF<<<1, 256, 0, stream>>>(Bp, gamma, out);
}

// Round 7
// 102.113 us; speedup vs baseline: 1.7596x; 1.1426x over previous
//
#include <hip/hip_runtime.h>
#include <hip/hip_bf16.h>
#include <math.h>

#define N1 512
#define N2 512
#define DIN 1280
#define DD 100
#define HH 20
#define NPIX (N1*N2)
#define PB 57

typedef short bf16x8 __attribute__((ext_vector_type(8)));
typedef float f32x4 __attribute__((ext_vector_type(4)));

// workspace layout in floats
static constexpr size_t WS_PP    = 0;                      // 2*1024*100 = 204800
static constexpr size_t WS_W1T   = 204800;                 // 1280*100 = 128000
static constexpr size_t WS_W2B   = 332800;                 // 224*32 ushort -> pad 4096
static constexpr size_t WS_M     = 336896;                 // 20*512*512 = 5242880
static constexpr size_t WS_PART  = WS_M + 5242880;         // 5*262144 = 1310720
static constexpr size_t WS_CRAW  = WS_PART + 1310720;      // 262144
static constexpr size_t WS_STATS = WS_CRAW + 262144;       // 64
static constexpr size_t WS_B     = WS_STATS + 64;          // 57*57 = 3249

// ---- prologue: transpose W1 -> w1t[k][h] (LDS-tiled, coalesced both sides),
//      build bf16 W2^T [224][32], zero stats
__global__ __launch_bounds__(256) void kP(const float* __restrict__ W1,
                                          const float* __restrict__ W2,
                                          float* __restrict__ w1t,
                                          unsigned short* __restrict__ w2b,
                                          float* __restrict__ stats) {
  const int tid = threadIdx.x;
  if (blockIdx.x >= 160) {   // w2b + stats
    int idx = (blockIdx.x - 160) * 256 + tid;
    if (blockIdx.x == 160 && tid < 64) stats[tid] = 0.0f;
    if (idx < 224 * 32) {
      int k = idx >> 5, n = idx & 31;
      float v = (n < HH && k < 200) ? W2[n * 200 + k] : 0.0f;
      __hip_bfloat16 b = __float2bfloat16(v);
      w2b[idx] = *reinterpret_cast<unsigned short*>(&b);
    }
    return;
  }
  __shared__ float sT[32][33];
  const int bx = blockIdx.x % 40, by = blockIdx.x / 40;  // k-tile, h-tile
  const int tx = tid & 31, ty = tid >> 5;
#pragma unroll
  for (int e = 0; e < 4; ++e) {
    int h = by * 32 + ty + e * 8, k = bx * 32 + tx;
    sT[ty + e * 8][tx] = (h < DD) ? W1[(size_t)h * DIN + k] : 0.0f;
  }
  __syncthreads();
#pragma unroll
  for (int e = 0; e < 4; ++e) {
    int k = bx * 32 + ty + e * 8, h = by * 32 + tx;
    if (h < DD) w1t[(size_t)k * DD + h] = sT[tx][ty + e * 8];
  }
}

// ---- projection partials via transposed W1 (coalesced): pp[kh][row][h], kh in 0..1
// block = 2 rows x 4 waves (2 h-halves x 2 K-halves of 640)
__global__ __launch_bounds__(256) void kA(const float* __restrict__ x1,
                                          const float* __restrict__ x2,
                                          const float* __restrict__ w1t,
                                          float* __restrict__ pp) {
  const int tid = threadIdx.x;
  const int w  = __builtin_amdgcn_readfirstlane(tid >> 6);  // wave id 0..3
  const int hh = w & 1, kh = w >> 1;
  const int h = hh * 64 + (tid & 63);
  if (h >= DD) return;
  const int r0 = blockIdx.x * 2;
  const float* xb = (r0 < N1) ? (x1 + (size_t)r0 * DIN) : (x2 + (size_t)(r0 - N1) * DIN);
  const float* xr0 = xb + kh * 640;
  const float* xr1 = xb + DIN + kh * 640;
  const float* w1p = w1t + (size_t)kh * 640 * DD + h;
  float a00 = 0.f, a01 = 0.f, a10 = 0.f, a11 = 0.f;
#pragma unroll 8
  for (int k = 0; k < 640; k += 2) {
    float wA = w1p[(size_t)k * DD];
    float wB = w1p[(size_t)(k + 1) * DD];
    float x00 = xr0[k], x01 = xr0[k + 1];
    float x10 = xr1[k], x11 = xr1[k + 1];
    a00 = fmaf(wA, x00, a00); a01 = fmaf(wB, x01, a01);
    a10 = fmaf(wA, x10, a10); a11 = fmaf(wB, x11, a11);
  }
  pp[(size_t)kh * 102400 + (size_t)r0 * DD + h] = a00 + a01;
  pp[(size_t)kh * 102400 + (size_t)(r0 + 1) * DD + h] = a10 + a11;
}

// ---- pairwise features + FC2 via MFMA bf16 + BN1 stats
// block = 8 i-rows x 64 j-cols, 4 waves (16-j slice each); grid 64x8 = 512 (2 blocks/CU)
__global__ __launch_bounds__(256, 2) void kB(const float* __restrict__ pp,
                                             const float* __restrict__ b1,
                                             const unsigned short* __restrict__ w2b,
                                             float* __restrict__ m,
                                             float* __restrict__ stats) {
  __shared__ float sA[8][132];    // a-rows, zero-padded cols 100..131
  __shared__ float sC[64][132];
  __shared__ float wred[4][40];
  const int tid = threadIdx.x;
  const int bi = blockIdx.x >> 3, bj = blockIdx.x & 7;   // 64 i-tiles x 8 j-tiles
  for (int idx = tid; idx < 72 * 33; idx += 256) {
    int r = idx / 33, d4 = idx % 33;
    float4 v = {0.f, 0.f, 0.f, 0.f};
    if (d4 < 25) {
      size_t row = (r < 8) ? (size_t)(bi * 8 + r) : (size_t)(N1 + bj * 64 + (r - 8));
      const float* base = pp + row * DD;
      float4 a0 = ((const float4*)base)[d4];
      float4 a1 = ((const float4*)(base + 102400))[d4];
      float4 bb = ((const float4*)b1)[d4];
      v.x = a0.x + a1.x + bb.x;
      v.y = a0.y + a1.y + bb.y;
      v.z = a0.z + a1.z + bb.z;
      v.w = a0.w + a1.w + bb.w;
    }
    if (r < 8) *(float4*)&sA[r][4 * d4] = v;
    else       *(float4*)&sC[r - 8][4 * d4] = v;
  }
  __syncthreads();

  const int w    = tid >> 6;     // wave 0..3
  const int lane = tid & 63;
  const int ln   = lane & 15;    // MFMA n-index
  const int q    = lane >> 4;    // k-quad
  const int jj   = w * 16 + ln;  // j within 64-tile

  // weight A-frags: lane supplies A[m=ln][k=8q+e] = w2b[k][ln(+16)]
  bf16x8 af[7][2];
#pragma unroll
  for (int ks = 0; ks < 7; ++ks)
#pragma unroll
    for (int t = 0; t < 2; ++t) {
      bf16x8 v;
#pragma unroll
      for (int e = 0; e < 8; ++e)
        v[e] = (short)w2b[(ks * 32 + q * 8 + e) * 32 + ln + 16 * t];
      af[ks][t] = v;
    }

  // per-lane c chunks: half hx covers k = 32*(hx>>1) + 8q + 4*(hx&1)
  int dOf[14];
  bool isP[14];
  float4 cH[14];
#pragma unroll
  for (int hx = 0; hx < 14; ++hx) {
    int kk = (hx >> 1) * 32 + q * 8 + (hx & 1) * 4;
    bool p = kk >= 100;
    isP[hx] = p;
    int d = p ? kk - 100 : kk;
    dOf[hx] = d;
    cH[hx] = *(const float4*)&sC[jj][d];
  }

  float st_s[8], st_q[8];
#pragma unroll
  for (int r = 0; r < 8; ++r) { st_s[r] = 0.f; st_q[r] = 0.f; }

  const int gj = bj * 64 + jj;
#pragma unroll 1
  for (int ii = 0; ii < 8; ++ii) {
    bf16x8 bf[7];
#pragma unroll
    for (int ks = 0; ks < 7; ++ks) {
      float4 a0 = *(const float4*)&sA[ii][dOf[2 * ks]];      // 16-lane broadcast reads
      float4 a1 = *(const float4*)&sA[ii][dOf[2 * ks + 1]];
      float4 c0 = cH[2 * ks], c1 = cH[2 * ks + 1];
      float f0 = isP[2*ks]   ? a0.x * c0.x : fabsf(a0.x - c0.x);
      float f1 = isP[2*ks]   ? a0.y * c0.y : fabsf(a0.y - c0.y);
      float f2 = isP[2*ks]   ? a0.z * c0.z : fabsf(a0.z - c0.z);
      float f3 = isP[2*ks]   ? a0.w * c0.w : fabsf(a0.w - c0.w);
      float f4 = isP[2*ks+1] ? a1.x * c1.x : fabsf(a1.x - c1.x);
      float f5 = isP[2*ks+1] ? a1.y * c1.y : fabsf(a1.y - c1.y);
      float f6 = isP[2*ks+1] ? a1.z * c1.z : fabsf(a1.z - c1.z);
      float f7 = isP[2*ks+1] ? a1.w * c1.w : fabsf(a1.w - c1.w);
      union { bf16x8 v; __hip_bfloat162 h2[4]; } u;
      u.h2[0] = __float22bfloat162_rn(make_float2(f0, f1));
      u.h2[1] = __float22bfloat162_rn(make_float2(f2, f3));
      u.h2[2] = __float22bfloat162_rn(make_float2(f4, f5));
      u.h2[3] = __float22bfloat162_rn(make_float2(f6, f7));
      bf[ks] = u.v;
    }
    f32x4 acc0 = {0.f, 0.f, 0.f, 0.f}, acc1 = {0.f, 0.f, 0.f, 0.f};
#pragma unroll
    for (int ks = 0; ks < 7; ++ks) {
      acc0 = __builtin_amdgcn_mfma_f32_16x16x32_bf16(af[ks][0], bf[ks], acc0, 0, 0, 0);
      acc1 = __builtin_amdgcn_mfma_f32_16x16x32_bf16(af[ks][1], bf[ks], acc1, 0, 0, 0);
    }
    // D: row h = 4q+r (+16 tile1), col j = ln  [verified m89 C/D mapping]
    const size_t pix = (size_t)(bi * 8 + ii) * N2 + gj;
#pragma unroll
    for (int r = 0; r < 4; ++r) {
      m[(size_t)(4 * q + r) * NPIX + pix] = acc0[r];
      st_s[r] += acc0[r];
      st_q[r] += acc0[r] * acc0[r];
    }
    if (q == 0) {
#pragma unroll
      for (int r = 0; r < 4; ++r)
        m[(size_t)(16 + r) * NPIX + pix] = acc1[r];
    }
#pragma unroll
    for (int r = 0; r < 4; ++r) {       // rows h>=20 are exact zeros
      st_s[4 + r] += acc1[r];
      st_q[4 + r] += acc1[r] * acc1[r];
    }
  }
#pragma unroll
  for (int r = 0; r < 8; ++r) {
#pragma unroll
    for (int off = 1; off < 16; off <<= 1) {
      st_s[r] += __shfl_xor(st_s[r], off);
      st_q[r] += __shfl_xor(st_q[r], off);
    }
  }
  if (ln == 0) {
#pragma unroll
    for (int r = 0; r < 4; ++r) {
      wred[w][4 * q + r]      = st_s[r];
      wred[w][20 + 4 * q + r] = st_q[r];
    }
    if (q == 0) {
#pragma unroll
      for (int r = 0; r < 4; ++r) {
        wred[w][16 + r] = st_s[4 + r];
        wred[w][36 + r] = st_q[4 + r];
      }
    }
  }
  __syncthreads();
  if (tid < 40)
    atomicAdd(&stats[tid], wred[0][tid] + wred[1][tid] + wred[2][tid] + wred[3][tid]);
}

// ---- conv 7x7, 4 channels per block (5-way split), BN1+relu at staging
__global__ __launch_bounds__(256, 4) void kD(const float* __restrict__ m,
                                             const float* __restrict__ bn1g,
                                             const float* __restrict__ bn1b,
                                             const float* __restrict__ cw,
                                             const float* __restrict__ stats,
                                             float* __restrict__ part) {
  __shared__ float sIn[4][38][40];
  __shared__ float sSc[4], sSh[4];
  const int tid = threadIdx.x;
  const int cs = blockIdx.y;               // channel chunk 0..4
  if (tid < 4) {
    int ch = cs * 4 + tid;
    float s = stats[ch], q = stats[HH + ch];
    float mu = s * (1.0f / NPIX);
    float var = q * (1.0f / NPIX) - mu * mu;
    float g = bn1g[ch] / sqrtf(var + 1e-5f);
    sSc[tid] = g;
    sSh[tid] = bn1b[ch] - mu * g;
  }
  __syncthreads();
  const int by = (blockIdx.x >> 4) * 32, bx = (blockIdx.x & 15) * 32;
  for (int idx = tid; idx < 4 * 38 * 40; idx += 256) {
    int ch4 = idx / 1520, rem = idx % 1520;
    int r = rem / 40, c = rem % 40;
    int gy = by + r - 3, gx = bx + c - 4;
    float v = 0.0f;
    if (gy >= 0 && gy < N1 && gx >= 0 && gx < N2)
      v = fmaxf(m[(size_t)(cs * 4 + ch4) * NPIX + (size_t)gy * N2 + gx] * sSc[ch4] + sSh[ch4], 0.0f);
    sIn[ch4][r][c] = v;
  }
  __syncthreads();
  const int ty = tid >> 4, tx = tid & 15;
  float acc00 = 0.f, acc01 = 0.f, acc10 = 0.f, acc11 = 0.f;
#pragma unroll 1
  for (int ch4 = 0; ch4 < 4; ++ch4) {
    float2 wv[8][5];
#pragma unroll
    for (int rr = 0; rr < 8; ++rr)
#pragma unroll
      for (int qq = 0; qq < 5; ++qq)
        wv[rr][qq] = *(const float2*)&sIn[ch4][2 * ty + rr][2 * tx + 2 * qq];
    const float* wch = cw + (cs * 4 + ch4) * 49;   // uniform -> s_load
#pragma unroll
    for (int ky = 0; ky < 7; ++ky)
#pragma unroll
      for (int kx = 0; kx < 7; ++kx) {
        float wt = wch[ky * 7 + kx];
        float e0 = ((kx + 1) & 1) ? wv[ky][(kx + 1) >> 1].y : wv[ky][(kx + 1) >> 1].x;
        float e1 = ((kx + 2) & 1) ? wv[ky][(kx + 2) >> 1].y : wv[ky][(kx + 2) >> 1].x;
        float f0 = ((kx + 1) & 1) ? wv[ky + 1][(kx + 1) >> 1].y : wv[ky + 1][(kx + 1) >> 1].x;
        float f1 = ((kx + 2) & 1) ? wv[ky + 1][(kx + 2) >> 1].y : wv[ky + 1][(kx + 2) >> 1].x;
        acc00 = fmaf(e0, wt, acc00);
        acc01 = fmaf(e1, wt, acc01);
        acc10 = fmaf(f0, wt, acc10);
        acc11 = fmaf(f1, wt, acc11);
      }
  }
  const int oy = by + 2 * ty, ox = bx + 2 * tx;
  float2 r0 = {acc00, acc01}, r1 = {acc10, acc11};
  float* dst = part + (size_t)cs * NPIX;
  *(float2*)&dst[(size_t)oy * N2 + ox] = r0;
  *(float2*)&dst[(size_t)(oy + 1) * N2 + ox] = r1;
}

// ---- sum partials -> Craw + BN2 stats
__global__ __launch_bounds__(256) void kE1(const float* __restrict__ part,
                                           float* __restrict__ stats,
                                           float* __restrict__ Craw) {
  __shared__ float wred[4][2];
  const int i = blockIdx.x * 256 + threadIdx.x;
  float s5 = part[i] + part[NPIX + i] + part[2 * NPIX + i] + part[3 * NPIX + i] + part[4 * NPIX + i];
  Craw[i] = s5;
  float s = s5, q = s5 * s5;
  const int lane = threadIdx.x & 63, wv = threadIdx.x >> 6;
#pragma unroll
  for (int off = 32; off; off >>= 1) {
    s += __shfl_xor(s, off);
    q += __shfl_xor(q, off);
  }
  if (lane == 0) { wred[wv][0] = s; wred[wv][1] = q; }
  __syncthreads();
  if (threadIdx.x < 2) {
    float v = wred[0][threadIdx.x] + wred[1][threadIdx.x] + wred[2][threadIdx.x] + wred[3][threadIdx.x];
    atomicAdd(&stats[2 * HH + threadIdx.x], v);
  }
}

// ---- fused BN2 + sigmoid + maxpool: one wave per 9x9 window
__global__ __launch_bounds__(256) void kE2M(const float* __restrict__ Craw,
                                            const float* __restrict__ stats,
                                            const float* __restrict__ bn2g,
                                            const float* __restrict__ bn2b,
                                            float* __restrict__ Cout,
                                            float* __restrict__ B) {
  const int w = blockIdx.x * 4 + (threadIdx.x >> 6);
  const int lane = threadIdx.x & 63;
  float s = stats[2 * HH], q = stats[2 * HH + 1];
  float mu = s * (1.0f / NPIX);
  float var = q * (1.0f / NPIX) - mu * mu;
  float g = bn2g[0] / sqrtf(var + 1e-5f);
  float b = bn2b[0] - mu * g;
  if (w >= PB * PB) return;
  const int wy = w / PB, wx = w % PB;
  const int y0 = wy * 9 - 4, x0 = wx * 9 - 4;
  float mx = -1e30f;
  for (int e = lane; e < 144; e += 64) {
    int dy = e / 12, dx = e % 12;
    int y = y0 + dy, x = x0 + dx;
    bool inWin = (dy < 9) && (dx < 9);
    bool claim = (y >= 0) && (y < N1) && (x >= 0) && (x < N2) &&
                 (dy < 9 || wy == PB - 1) && (dx < 9 || wx == PB - 1);
    if (claim) {
      float z = Craw[(size_t)y * N2 + x] * g + b;
      float sg = 1.0f / (1.0f + expf(-z));
      Cout[(size_t)y * N2 + x] = sg;
      if (inWin) mx = fmaxf(mx, sg);
    }
  }
#pragma unroll
  for (int off = 32; off; off >>= 1) mx = fmaxf(mx, __shfl_xor(mx, off));
  if (lane == 0) B[w] = mx;
}

// ---- per-column mean/std(ddof=1), phat -> d_out[0]
__global__ __launch_bounds__(256) void kF(const float* __restrict__ B,
                                          const float* __restrict__ gamma,
                                          float* __restrict__ out0) {
  __shared__ float sB[PB * PB];
  __shared__ float cm[PB], cs[PB];
  __shared__ float r1[4], r2[4];
  const int tid = threadIdx.x;
  for (int i = tid; i < PB * PB; i += 256) sB[i] = B[i];
  __syncthreads();
  if (tid < PB) {
    float s = 0.0f;
    for (int h = 0; h < PB; ++h) s += sB[h * PB + tid];
    float mean = s / (float)PB;
    float v = 0.0f;
    for (int h = 0; h < PB; ++h) { float d = sB[h * PB + tid] - mean; v += d * d; }
    cm[tid] = mean;
    cs[tid] = sqrtf(v / (float)(PB - 1) + 1e-5f);
  }
  __syncthreads();
  const float g = gamma[0];
  float sq = 0.0f, cnt = 0.0f;
  for (int i = tid; i < PB * PB; i += 256) {
    int w = i % PB;
    float qv = sB[i] - cm[w] - g * cs[w];
    if (qv > 0.0f) { sq += qv; cnt += 1.0f; }
  }
#pragma unroll
  for (int off = 32; off; off >>= 1) {
    sq += __shfl_xor(sq, off);
    cnt += __shfl_xor(cnt, off);
  }
  if ((tid & 63) == 0) { r1[tid >> 6] = sq; r2[tid >> 6] = cnt; }
  __syncthreads();
  if (tid == 0) {
    float S = r1[0] + r1[1] + r1[2] + r1[3];
    float Cn = r2[0] + r2[1] + r2[2] + r2[3];
    float phat = S / (Cn + 1.0f);
    float sig = 1.0f / (1.0f + expf(-phat));
    out0[0] = fminf(fmaxf(sig, 0.0f), 1.0f);
  }
}

extern "C" void kernel_launch(void* const* d_in, const int* in_sizes, int n_in,
                              void* d_out, int out_size, void* d_ws, size_t ws_size,
                              hipStream_t stream) {
  const float* x1    = (const float*)d_in[0];
  const float* x2    = (const float*)d_in[1];
  const float* W1    = (const float*)d_in[2];
  const float* b1    = (const float*)d_in[3];
  const float* W2    = (const float*)d_in[4];
  // d_in[5] = b2   : cancels through BN1 (training-mode mean subtraction)
  const float* bn1g  = (const float*)d_in[6];
  const float* bn1b  = (const float*)d_in[7];
  const float* convw = (const float*)d_in[8];
  // d_in[9] = conv_b : cancels through BN2
  const float* bn2g  = (const float*)d_in[10];
  const float* bn2b  = (const float*)d_in[11];
  const float* gamma = (const float*)d_in[12];

  float* ws    = (float*)d_ws;
  float* pp    = ws + WS_PP;
  float* w1t   = ws + WS_W1T;
  unsigned short* w2b = (unsigned short*)(ws + WS_W2B);
  float* m     = ws + WS_M;
  float* part  = ws + WS_PART;
  float* Craw  = ws + WS_CRAW;
  float* stats = ws + WS_STATS;
  float* Bp    = ws + WS_B;
  float* out   = (float*)d_out;

  kP<<<188, 256, 0, stream>>>(W1, W2, w1t, w2b, stats);
  kA<<<512, 256, 0, stream>>>(x1, x2, w1t, pp);
  kB<<<512, 256, 0, stream>>>(pp, b1, w2b, m, stats);
  kD<<<dim3(256, 5), 256, 0, stream>>>(m, bn1g, bn1b, convw, stats, part);
  kE1<<<1024, 256, 0, stream>>>(part, stats, Craw);
  kE2M<<<(PB * PB + 3) / 4, 256, 0, stream>>>(Craw, stats, bn2g, bn2b, out + 1, Bp);
  kF<<<1, 256, 0, stream>>>(Bp, gamma, out);
}

// Round 8
// 92.985 us; speedup vs baseline: 1.9324x; 1.0982x over previous
//
#include <hip/hip_runtime.h>
#include <hip/hip_bf16.h>
#include <math.h>

#define N1 512
#define N2 512
#define DIN 1280
#define DD 100
#define HH 20
#define NPIX (N1*N2)
#define PB 57

typedef short bf16x8 __attribute__((ext_vector_type(8)));
typedef float f32x4 __attribute__((ext_vector_type(4)));

// workspace layout in floats
static constexpr size_t WS_PP    = 0;                      // 2*1024*100 = 204800
static constexpr size_t WS_W1T   = 204800;                 // 1280*100 = 128000
static constexpr size_t WS_W2B   = 332800;                 // 224*32 ushort -> pad 4096
static constexpr size_t WS_M     = 336896;                 // 20*512*512 = 5242880
static constexpr size_t WS_CRAW  = WS_M + 5242880;         // 262144
static constexpr size_t WS_STATS = WS_CRAW + 262144;       // 64
static constexpr size_t WS_B     = WS_STATS + 64;          // 57*57

// ---- prologue: transpose W1 -> w1t[k][h], build bf16 W2^T [224][32], zero stats
__global__ __launch_bounds__(256) void kP(const float* __restrict__ W1,
                                          const float* __restrict__ W2,
                                          float* __restrict__ w1t,
                                          unsigned short* __restrict__ w2b,
                                          float* __restrict__ stats) {
  const int tid = threadIdx.x;
  if (blockIdx.x >= 160) {   // w2b + stats
    int idx = (blockIdx.x - 160) * 256 + tid;
    if (blockIdx.x == 160 && tid < 64) stats[tid] = 0.0f;
    if (idx < 224 * 32) {
      int k = idx >> 5, n = idx & 31;
      float v = (n < HH && k < 200) ? W2[n * 200 + k] : 0.0f;
      __hip_bfloat16 b = __float2bfloat16(v);
      w2b[idx] = *reinterpret_cast<unsigned short*>(&b);
    }
    return;
  }
  __shared__ float sT[32][33];
  const int bx = blockIdx.x % 40, by = blockIdx.x / 40;  // k-tile, h-tile
  const int tx = tid & 31, ty = tid >> 5;
#pragma unroll
  for (int e = 0; e < 4; ++e) {
    int h = by * 32 + ty + e * 8, k = bx * 32 + tx;
    sT[ty + e * 8][tx] = (h < DD) ? W1[(size_t)h * DIN + k] : 0.0f;
  }
  __syncthreads();
#pragma unroll
  for (int e = 0; e < 4; ++e) {
    int k = bx * 32 + ty + e * 8, h = by * 32 + tx;
    if (h < DD) w1t[(size_t)k * DD + h] = sT[tx][ty + e * 8];
  }
}

// ---- projection partials: 8 rows/block (4x w1t reuse), k-split 2, coalesced w1t
__global__ __launch_bounds__(512) void kA(const float* __restrict__ x1,
                                          const float* __restrict__ x2,
                                          const float* __restrict__ w1t,
                                          float* __restrict__ pp) {
  const int tid = threadIdx.x;
  const int w  = __builtin_amdgcn_readfirstlane(tid >> 6);  // wave 0..7
  const int rp = w >> 1, hh = w & 1;
  const int h = hh * 64 + (tid & 63);
  if (h >= DD) return;
  const int kh = blockIdx.x & 1;
  const int rb = (blockIdx.x >> 1) * 8;
  const int r0 = rb + rp * 2;
  const float* xb = (r0 < N1) ? (x1 + (size_t)r0 * DIN) : (x2 + (size_t)(r0 - N1) * DIN);
  const float* xr0 = xb + kh * 640;
  const float* xr1 = xb + DIN + kh * 640;
  const float* w1p = w1t + (size_t)kh * 640 * DD + h;
  float a00 = 0.f, a01 = 0.f, a10 = 0.f, a11 = 0.f;
#pragma unroll 8
  for (int k = 0; k < 640; k += 2) {
    float wA = w1p[(size_t)k * DD];
    float wB = w1p[(size_t)(k + 1) * DD];
    float x00 = xr0[k], x01 = xr0[k + 1];
    float x10 = xr1[k], x11 = xr1[k + 1];
    a00 = fmaf(wA, x00, a00); a01 = fmaf(wB, x01, a01);
    a10 = fmaf(wA, x10, a10); a11 = fmaf(wB, x11, a11);
  }
  pp[(size_t)kh * 102400 + (size_t)r0 * DD + h] = a00 + a01;
  pp[(size_t)kh * 102400 + (size_t)(r0 + 1) * DD + h] = a10 + a11;
}

// ---- pairwise features + FC2 via MFMA bf16 + BN1 stats (unchanged from R7)
__global__ __launch_bounds__(256, 2) void kB(const float* __restrict__ pp,
                                             const float* __restrict__ b1,
                                             const unsigned short* __restrict__ w2b,
                                             float* __restrict__ m,
                                             float* __restrict__ stats) {
  __shared__ float sA[8][132];
  __shared__ float sC[64][132];
  __shared__ float wred[4][40];
  const int tid = threadIdx.x;
  const int bi = blockIdx.x >> 3, bj = blockIdx.x & 7;
  for (int idx = tid; idx < 72 * 33; idx += 256) {
    int r = idx / 33, d4 = idx % 33;
    float4 v = {0.f, 0.f, 0.f, 0.f};
    if (d4 < 25) {
      size_t row = (r < 8) ? (size_t)(bi * 8 + r) : (size_t)(N1 + bj * 64 + (r - 8));
      const float* base = pp + row * DD;
      float4 a0 = ((const float4*)base)[d4];
      float4 a1 = ((const float4*)(base + 102400))[d4];
      float4 bb = ((const float4*)b1)[d4];
      v.x = a0.x + a1.x + bb.x;
      v.y = a0.y + a1.y + bb.y;
      v.z = a0.z + a1.z + bb.z;
      v.w = a0.w + a1.w + bb.w;
    }
    if (r < 8) *(float4*)&sA[r][4 * d4] = v;
    else       *(float4*)&sC[r - 8][4 * d4] = v;
  }
  __syncthreads();

  const int w    = tid >> 6;
  const int lane = tid & 63;
  const int ln   = lane & 15;
  const int q    = lane >> 4;
  const int jj   = w * 16 + ln;

  bf16x8 af[7][2];
#pragma unroll
  for (int ks = 0; ks < 7; ++ks)
#pragma unroll
    for (int t = 0; t < 2; ++t) {
      bf16x8 v;
#pragma unroll
      for (int e = 0; e < 8; ++e)
        v[e] = (short)w2b[(ks * 32 + q * 8 + e) * 32 + ln + 16 * t];
      af[ks][t] = v;
    }

  int dOf[14];
  bool isP[14];
  float4 cH[14];
#pragma unroll
  for (int hx = 0; hx < 14; ++hx) {
    int kk = (hx >> 1) * 32 + q * 8 + (hx & 1) * 4;
    bool p = kk >= 100;
    isP[hx] = p;
    int d = p ? kk - 100 : kk;
    dOf[hx] = d;
    cH[hx] = *(const float4*)&sC[jj][d];
  }

  float st_s[8], st_q[8];
#pragma unroll
  for (int r = 0; r < 8; ++r) { st_s[r] = 0.f; st_q[r] = 0.f; }

  const int gj = bj * 64 + jj;
#pragma unroll 1
  for (int ii = 0; ii < 8; ++ii) {
    bf16x8 bf[7];
#pragma unroll
    for (int ks = 0; ks < 7; ++ks) {
      float4 a0 = *(const float4*)&sA[ii][dOf[2 * ks]];
      float4 a1 = *(const float4*)&sA[ii][dOf[2 * ks + 1]];
      float4 c0 = cH[2 * ks], c1 = cH[2 * ks + 1];
      float f0 = isP[2*ks]   ? a0.x * c0.x : fabsf(a0.x - c0.x);
      float f1 = isP[2*ks]   ? a0.y * c0.y : fabsf(a0.y - c0.y);
      float f2 = isP[2*ks]   ? a0.z * c0.z : fabsf(a0.z - c0.z);
      float f3 = isP[2*ks]   ? a0.w * c0.w : fabsf(a0.w - c0.w);
      float f4 = isP[2*ks+1] ? a1.x * c1.x : fabsf(a1.x - c1.x);
      float f5 = isP[2*ks+1] ? a1.y * c1.y : fabsf(a1.y - c1.y);
      float f6 = isP[2*ks+1] ? a1.z * c1.z : fabsf(a1.z - c1.z);
      float f7 = isP[2*ks+1] ? a1.w * c1.w : fabsf(a1.w - c1.w);
      union { bf16x8 v; __hip_bfloat162 h2[4]; } u;
      u.h2[0] = __float22bfloat162_rn(make_float2(f0, f1));
      u.h2[1] = __float22bfloat162_rn(make_float2(f2, f3));
      u.h2[2] = __float22bfloat162_rn(make_float2(f4, f5));
      u.h2[3] = __float22bfloat162_rn(make_float2(f6, f7));
      bf[ks] = u.v;
    }
    f32x4 acc0 = {0.f, 0.f, 0.f, 0.f}, acc1 = {0.f, 0.f, 0.f, 0.f};
#pragma unroll
    for (int ks = 0; ks < 7; ++ks) {
      acc0 = __builtin_amdgcn_mfma_f32_16x16x32_bf16(af[ks][0], bf[ks], acc0, 0, 0, 0);
      acc1 = __builtin_amdgcn_mfma_f32_16x16x32_bf16(af[ks][1], bf[ks], acc1, 0, 0, 0);
    }
    const size_t pix = (size_t)(bi * 8 + ii) * N2 + gj;
#pragma unroll
    for (int r = 0; r < 4; ++r) {
      m[(size_t)(4 * q + r) * NPIX + pix] = acc0[r];
      st_s[r] += acc0[r];
      st_q[r] += acc0[r] * acc0[r];
    }
    if (q == 0) {
#pragma unroll
      for (int r = 0; r < 4; ++r)
        m[(size_t)(16 + r) * NPIX + pix] = acc1[r];
    }
#pragma unroll
    for (int r = 0; r < 4; ++r) {
      st_s[4 + r] += acc1[r];
      st_q[4 + r] += acc1[r] * acc1[r];
    }
  }
#pragma unroll
  for (int r = 0; r < 8; ++r) {
#pragma unroll
    for (int off = 1; off < 16; off <<= 1) {
      st_s[r] += __shfl_xor(st_s[r], off);
      st_q[r] += __shfl_xor(st_q[r], off);
    }
  }
  if (ln == 0) {
#pragma unroll
    for (int r = 0; r < 4; ++r) {
      wred[w][4 * q + r]      = st_s[r];
      wred[w][20 + 4 * q + r] = st_q[r];
    }
    if (q == 0) {
#pragma unroll
      for (int r = 0; r < 4; ++r) {
        wred[w][16 + r] = st_s[4 + r];
        wred[w][36 + r] = st_q[4 + r];
      }
    }
  }
  __syncthreads();
  if (tid < 40)
    atomicAdd(&stats[tid], wred[0][tid] + wred[1][tid] + wred[2][tid] + wred[3][tid]);
}

// ---- conv 7x7, ALL 20 channels per block (5 chunks, LDS dbuf + reg-staged loads),
//      BN1+relu at staging; writes Craw + BN2 stats (kE1 eliminated)
__global__ __launch_bounds__(256, 1) void kD(const float* __restrict__ m,
                                             const float* __restrict__ bn1g,
                                             const float* __restrict__ bn1b,
                                             const float* __restrict__ cw,
                                             float* __restrict__ stats,
                                             float* __restrict__ Craw) {
  __shared__ float sIn[2][4][38][40];
  __shared__ float sSc[HH], sSh[HH];
  __shared__ float wsum[4][2];
  const int tid = threadIdx.x;
  if (tid < HH) {
    float s = stats[tid], q = stats[HH + tid];
    float mu = s * (1.0f / NPIX);
    float var = q * (1.0f / NPIX) - mu * mu;
    float g = bn1g[tid] / sqrtf(var + 1e-5f);
    sSc[tid] = g;
    sSh[tid] = bn1b[tid] - mu * g;
  }
  const int by = (blockIdx.x >> 4) * 32, bx = (blockIdx.x & 15) * 32;
  const int w = tid >> 6, lane = tid & 63;
  const int gxs = bx + lane - 4;
  const bool colOk = (lane < 40) && (gxs >= 0) && (gxs < N2);
  float ld[38];
  {   // prologue: chunk 0 loads (independent of sSc)
    const float* mp = m + (size_t)w * NPIX + gxs;
#pragma unroll
    for (int r = 0; r < 38; ++r) {
      int gy = by + r - 3;
      ld[r] = (colOk && gy >= 0 && gy < N1) ? mp[(size_t)gy * N2] : 0.0f;
    }
  }
  __syncthreads();   // sSc/sSh ready
  if (lane < 40) {
    float sc = sSc[w], sh = sSh[w];
#pragma unroll
    for (int r = 0; r < 38; ++r) {
      int gy = by + r - 3;
      bool ok = colOk && gy >= 0 && gy < N1;
      sIn[0][w][r][lane] = ok ? fmaxf(fmaf(ld[r], sc, sh), 0.0f) : 0.0f;
    }
  }
  __syncthreads();
  const int ty = tid >> 4, tx = tid & 15;
  float acc00 = 0.f, acc01 = 0.f, acc10 = 0.f, acc11 = 0.f;
#pragma unroll 1
  for (int cc = 0; cc < 5; ++cc) {
    if (cc < 4) {   // issue next chunk's loads early (overlap with compute)
      const float* mp = m + (size_t)((cc + 1) * 4 + w) * NPIX + gxs;
#pragma unroll
      for (int r = 0; r < 38; ++r) {
        int gy = by + r - 3;
        ld[r] = (colOk && gy >= 0 && gy < N1) ? mp[(size_t)gy * N2] : 0.0f;
      }
    }
    const int cur = cc & 1;
#pragma unroll 1
    for (int ch4 = 0; ch4 < 4; ++ch4) {
      float2 win[8][5];
#pragma unroll
      for (int rr = 0; rr < 8; ++rr)
#pragma unroll
        for (int qq = 0; qq < 5; ++qq)
          win[rr][qq] = *(const float2*)&sIn[cur][ch4][2 * ty + rr][2 * tx + 2 * qq];
      const float* wch = cw + (cc * 4 + ch4) * 49;   // uniform -> s_load
#pragma unroll
      for (int ky = 0; ky < 7; ++ky)
#pragma unroll
        for (int kx = 0; kx < 7; ++kx) {
          float wt = wch[ky * 7 + kx];
          float e0 = ((kx + 1) & 1) ? win[ky][(kx + 1) >> 1].y : win[ky][(kx + 1) >> 1].x;
          float e1 = ((kx + 2) & 1) ? win[ky][(kx + 2) >> 1].y : win[ky][(kx + 2) >> 1].x;
          float f0 = ((kx + 1) & 1) ? win[ky + 1][(kx + 1) >> 1].y : win[ky + 1][(kx + 1) >> 1].x;
          float f1 = ((kx + 2) & 1) ? win[ky + 1][(kx + 2) >> 1].y : win[ky + 1][(kx + 2) >> 1].x;
          acc00 = fmaf(e0, wt, acc00);
          acc01 = fmaf(e1, wt, acc01);
          acc10 = fmaf(f0, wt, acc10);
          acc11 = fmaf(f1, wt, acc11);
        }
    }
    __syncthreads();
    if (cc < 4 && lane < 40) {
      int ch = (cc + 1) * 4 + w;
      float sc = sSc[ch], sh = sSh[ch];
#pragma unroll
      for (int r = 0; r < 38; ++r) {
        int gy = by + r - 3;
        bool ok = colOk && gy >= 0 && gy < N1;
        sIn[cur ^ 1][w][r][lane] = ok ? fmaxf(fmaf(ld[r], sc, sh), 0.0f) : 0.0f;
      }
    }
    __syncthreads();
  }
  const int oy = by + 2 * ty, ox = bx + 2 * tx;
  float2 r0 = {acc00, acc01}, r1 = {acc10, acc11};
  *(float2*)&Craw[(size_t)oy * N2 + ox] = r0;
  *(float2*)&Craw[(size_t)(oy + 1) * N2 + ox] = r1;
  float s = acc00 + acc01 + acc10 + acc11;
  float q = acc00 * acc00 + acc01 * acc01 + acc10 * acc10 + acc11 * acc11;
#pragma unroll
  for (int off = 32; off; off >>= 1) {
    s += __shfl_xor(s, off);
    q += __shfl_xor(q, off);
  }
  if (lane == 0) { wsum[w][0] = s; wsum[w][1] = q; }
  __syncthreads();
  if (tid < 2) {
    float v = wsum[0][tid] + wsum[1][tid] + wsum[2][tid] + wsum[3][tid];
    atomicAdd(&stats[2 * HH + tid], v);
  }
}

// ---- fused BN2 + sigmoid + maxpool: one wave per 9x9 window
__global__ __launch_bounds__(256) void kE2M(const float* __restrict__ Craw,
                                            const float* __restrict__ stats,
                                            const float* __restrict__ bn2g,
                                            const float* __restrict__ bn2b,
                                            float* __restrict__ Cout,
                                            float* __restrict__ B) {
  const int w = blockIdx.x * 4 + (threadIdx.x >> 6);
  const int lane = threadIdx.x & 63;
  float s = stats[2 * HH], q = stats[2 * HH + 1];
  float mu = s * (1.0f / NPIX);
  float var = q * (1.0f / NPIX) - mu * mu;
  float g = bn2g[0] / sqrtf(var + 1e-5f);
  float b = bn2b[0] - mu * g;
  if (w >= PB * PB) return;
  const int wy = w / PB, wx = w % PB;
  const int y0 = wy * 9 - 4, x0 = wx * 9 - 4;
  float mx = -1e30f;
  for (int e = lane; e < 144; e += 64) {
    int dy = e / 12, dx = e % 12;
    int y = y0 + dy, x = x0 + dx;
    bool inWin = (dy < 9) && (dx < 9);
    bool claim = (y >= 0) && (y < N1) && (x >= 0) && (x < N2) &&
                 (dy < 9 || wy == PB - 1) && (dx < 9 || wx == PB - 1);
    if (claim) {
      float z = Craw[(size_t)y * N2 + x] * g + b;
      float sg = 1.0f / (1.0f + expf(-z));
      Cout[(size_t)y * N2 + x] = sg;
      if (inWin) mx = fmaxf(mx, sg);
    }
  }
#pragma unroll
  for (int off = 32; off; off >>= 1) mx = fmaxf(mx, __shfl_xor(mx, off));
  if (lane == 0) B[w] = mx;
}

// ---- per-column mean/std(ddof=1), phat -> d_out[0]; 16-lane-parallel columns
__global__ __launch_bounds__(1024) void kF(const float* __restrict__ B,
                                           const float* __restrict__ gamma,
                                           float* __restrict__ out0) {
  __shared__ float sB[PB * PB];
  __shared__ float cm[PB], cs[PB];
  __shared__ float r1[16], r2[16];
  const int tid = threadIdx.x;
  for (int i = tid; i < PB * PB; i += 1024) sB[i] = B[i];
  __syncthreads();
  if (tid < PB * 16) {
    int c = tid >> 4, g = tid & 15;
    float s = 0.0f;
    for (int h = g; h < PB; h += 16) s += sB[h * PB + c];
#pragma unroll
    for (int off = 1; off < 16; off <<= 1) s += __shfl_xor(s, off);
    float mean = s / (float)PB;
    float v = 0.0f;
    for (int h = g; h < PB; h += 16) { float d = sB[h * PB + c] - mean; v += d * d; }
#pragma unroll
    for (int off = 1; off < 16; off <<= 1) v += __shfl_xor(v, off);
    if (g == 0) {
      cm[c] = mean;
      cs[c] = sqrtf(v / (float)(PB - 1) + 1e-5f);
    }
  }
  __syncthreads();
  const float g = gamma[0];
  float sq = 0.0f, cnt = 0.0f;
  for (int i = tid; i < PB * PB; i += 1024) {
    int w = i % PB;
    float qv = sB[i] - cm[w] - g * cs[w];
    if (qv > 0.0f) { sq += qv; cnt += 1.0f; }
  }
#pragma unroll
  for (int off = 32; off; off >>= 1) {
    sq += __shfl_xor(sq, off);
    cnt += __shfl_xor(cnt, off);
  }
  if ((tid & 63) == 0) { r1[tid >> 6] = sq; r2[tid >> 6] = cnt; }
  __syncthreads();
  if (tid == 0) {
    float S = 0.f, Cn = 0.f;
#pragma unroll
    for (int e = 0; e < 16; ++e) { S += r1[e]; Cn += r2[e]; }
    float phat = S / (Cn + 1.0f);
    float sig = 1.0f / (1.0f + expf(-phat));
    out0[0] = fminf(fmaxf(sig, 0.0f), 1.0f);
  }
}

extern "C" void kernel_launch(void* const* d_in, const int* in_sizes, int n_in,
                              void* d_out, int out_size, void* d_ws, size_t ws_size,
                              hipStream_t stream) {
  const float* x1    = (const float*)d_in[0];
  const float* x2    = (const float*)d_in[1];
  const float* W1    = (const float*)d_in[2];
  const float* b1    = (const float*)d_in[3];
  const float* W2    = (const float*)d_in[4];
  // d_in[5] = b2   : cancels through BN1 (training-mode mean subtraction)
  const float* bn1g  = (const float*)d_in[6];
  const float* bn1b  = (const float*)d_in[7];
  const float* convw = (const float*)d_in[8];
  // d_in[9] = conv_b : cancels through BN2
  const float* bn2g  = (const float*)d_in[10];
  const float* bn2b  = (const float*)d_in[11];
  const float* gamma = (const float*)d_in[12];

  float* ws    = (float*)d_ws;
  float* pp    = ws + WS_PP;
  float* w1t   = ws + WS_W1T;
  unsigned short* w2b = (unsigned short*)(ws + WS_W2B);
  float* m     = ws + WS_M;
  float* Craw  = ws + WS_CRAW;
  float* stats = ws + WS_STATS;
  float* Bp    = ws + WS_B;
  float* out   = (float*)d_out;

  kP<<<188, 256, 0, stream>>>(W1, W2, w1t, w2b, stats);
  kA<<<256, 512, 0, stream>>>(x1, x2, w1t, pp);
  kB<<<512, 256, 0, stream>>>(pp, b1, w2b, m, stats);
  kD<<<256, 256, 0, stream>>>(m, bn1g, bn1b, convw, stats, Craw);
  kE2M<<<(PB * PB + 3) / 4, 256, 0, stream>>>(Craw, stats, bn2g, bn2b, out + 1, Bp);
  kF<<<1, 1024, 0, stream>>>(Bp, gamma, out);
}